// Round 3
// baseline (2426.062 us; speedup 1.0000x reference)
//
#include <hip/hip_runtime.h>
#include <hip/hip_bf16.h>

// GCN forward: CSR-by-dst build once, then 3x (GEMM -> gather-aggregate -> ReLU),
// binary-search mean-pool, MLP classifier.
// norm = dinv[src]*dinv[dst] factored: dinv[src] into GEMM epilogue,
// dinv[dst]+bias+relu into aggregate epilogue. Self-loop = accumulator init.

__global__ void count_kernel(const int* __restrict__ dst, int* __restrict__ cnt, int E) {
    int i = blockIdx.x * 256 + threadIdx.x;
    int e = i * 4;
    if (e + 4 <= E) {
        int4 d = ((const int4*)dst)[i];
        atomicAdd(&cnt[d.x], 1);
        atomicAdd(&cnt[d.y], 1);
        atomicAdd(&cnt[d.z], 1);
        atomicAdd(&cnt[d.w], 1);
    } else {
        for (; e < E; e++) atomicAdd(&cnt[dst[e]], 1);
    }
}

__global__ void dinv_kernel(const int* __restrict__ cnt, float* __restrict__ dinv, int N) {
    int i = blockIdx.x * 256 + threadIdx.x;
    if (i < N) dinv[i] = rsqrtf((float)(cnt[i] + 1));  // +1 = self loop
}

// exclusive scan, 2048 elems/block
__global__ void scanA(const int* __restrict__ cnt, int* __restrict__ rp,
                      int* __restrict__ bs, int N) {
    __shared__ int lds[256];
    int t = threadIdx.x;
    int base = blockIdx.x * 2048 + t * 8;
    int v[8]; int tsum = 0;
#pragma unroll
    for (int i = 0; i < 8; i++) { int idx = base + i; int x = (idx < N) ? cnt[idx] : 0; v[i] = x; tsum += x; }
    lds[t] = tsum; __syncthreads();
#pragma unroll
    for (int d = 1; d < 256; d <<= 1) {
        int x = (t >= d) ? lds[t - d] : 0; __syncthreads();
        lds[t] += x; __syncthreads();
    }
    int run = lds[t] - tsum;
#pragma unroll
    for (int i = 0; i < 8; i++) { int idx = base + i; if (idx < N) rp[idx] = run; run += v[i]; }
    if (t == 255) bs[blockIdx.x] = lds[255];
}

__global__ void scanB(int* bs, int* rp, int NB, int N) {
    if (threadIdx.x == 0 && blockIdx.x == 0) {
        int run = 0;
        for (int i = 0; i < NB; i++) { int x = bs[i]; bs[i] = run; run += x; }
        rp[N] = run;
    }
}

__global__ void scanC(int* __restrict__ rp, const int* __restrict__ bs, int N) {
    int base = blockIdx.x * 2048 + threadIdx.x * 8;
    int add = bs[blockIdx.x];
#pragma unroll
    for (int i = 0; i < 8; i++) { int j = base + i; if (j < N) rp[j] += add; }
}

// cursor pre-filled with rp via d2d copy: pos = atomicAdd(&cursor[d],1)
__global__ void fill_kernel(const int* __restrict__ src, const int* __restrict__ dst,
                            int* __restrict__ cursor, int* __restrict__ csr, int E) {
    int i = blockIdx.x * 256 + threadIdx.x;
    int e = i * 4;
    if (e + 4 <= E) {
        int4 d = ((const int4*)dst)[i];
        int4 s = ((const int4*)src)[i];
        int p0 = atomicAdd(&cursor[d.x], 1);
        int p1 = atomicAdd(&cursor[d.y], 1);
        int p2 = atomicAdd(&cursor[d.z], 1);
        int p3 = atomicAdd(&cursor[d.w], 1);
        csr[p0] = s.x; csr[p1] = s.y; csr[p2] = s.z; csr[p3] = s.w;
    } else {
        for (; e < E; e++) {
            int d = dst[e];
            int pos = atomicAdd(&cursor[d], 1);
            csr[pos] = src[e];
        }
    }
}

// G[row][j] = dinv[row] * sum_k X[row][k]*W[k][j]
// W column j held in lane-j VGPRs; X tile staged in LDS (contiguous rows).
template <int K, int RPW>
__global__ __launch_bounds__(256, 2) void gemm_dinv(const float* __restrict__ X,
                                                    const float* __restrict__ W,
                                                    const float* __restrict__ dinv,
                                                    float* __restrict__ G, int N) {
    constexpr int ROWS = 4 * RPW;
    __shared__ float Xl[ROWS * K];
    int lane = threadIdx.x & 63;
    int wid  = threadIdx.x >> 6;
    int row0 = blockIdx.x * ROWS;
    const float* xsrc = X + (size_t)row0 * K;

    if (row0 + ROWS <= N) {
#pragma unroll
        for (int i = threadIdx.x; i < ROWS * K / 4; i += 256)
            ((float4*)Xl)[i] = ((const float4*)xsrc)[i];
    } else {
        int avail = (N - row0) * K;
        for (int i = threadIdx.x; i < ROWS * K; i += 256)
            Xl[i] = (i < avail) ? xsrc[i] : 0.f;
    }

    float w[K];
#pragma unroll
    for (int k = 0; k < K; k++) w[k] = W[k * 64 + lane];
    __syncthreads();

    float acc[RPW];
#pragma unroll
    for (int r = 0; r < RPW; r++) acc[r] = 0.f;
    int rbase = wid * RPW;
#pragma unroll
    for (int k4 = 0; k4 < K / 4; k4++) {
        float4 xv[RPW];
#pragma unroll
        for (int r = 0; r < RPW; r++)
            xv[r] = *(const float4*)&Xl[(rbase + r) * K + k4 * 4];
#pragma unroll
        for (int r = 0; r < RPW; r++) {
            acc[r] = fmaf(xv[r].x, w[k4 * 4 + 0], acc[r]);
            acc[r] = fmaf(xv[r].y, w[k4 * 4 + 1], acc[r]);
            acc[r] = fmaf(xv[r].z, w[k4 * 4 + 2], acc[r]);
            acc[r] = fmaf(xv[r].w, w[k4 * 4 + 3], acc[r]);
        }
    }
#pragma unroll
    for (int r = 0; r < RPW; r++) {
        int row = row0 + rbase + r;
        if (row < N) G[(size_t)row * 64 + lane] = dinv[row] * acc[r];
    }
}

// H[node] = relu(dinv[node] * (G[node] + sum_{src} G[src]) + b)
// wave = 1 node; 4 groups x 16 lanes, each group handles one edge via float4.
__global__ __launch_bounds__(256) void aggregate(const float* __restrict__ G,
                                                 const int* __restrict__ rp,
                                                 const int* __restrict__ csr,
                                                 const float* __restrict__ dinv,
                                                 const float* __restrict__ bias,
                                                 float* __restrict__ H, int N) {
    int node = blockIdx.x * 4 + (threadIdx.x >> 6);
    if (node >= N) return;
    node = __builtin_amdgcn_readfirstlane(node);
    int lane = threadIdx.x & 63;
    int grp = lane >> 4, sub = lane & 15;
    int beg = rp[node], end = rp[node + 1];
    const float4* G4 = (const float4*)G;

    float4 acc = make_float4(0.f, 0.f, 0.f, 0.f);
    if (grp == 0) acc = G4[(size_t)node * 16 + sub];  // self loop

    int e = beg + grp;
    for (; e + 4 < end; e += 8) {
        int s0 = csr[e], s1 = csr[e + 4];
        float4 v0 = G4[(size_t)s0 * 16 + sub];
        float4 v1 = G4[(size_t)s1 * 16 + sub];
        acc.x += v0.x; acc.y += v0.y; acc.z += v0.z; acc.w += v0.w;
        acc.x += v1.x; acc.y += v1.y; acc.z += v1.z; acc.w += v1.w;
    }
    if (e < end) {
        int s0 = csr[e];
        float4 v0 = G4[(size_t)s0 * 16 + sub];
        acc.x += v0.x; acc.y += v0.y; acc.z += v0.z; acc.w += v0.w;
    }
#pragma unroll
    for (int m = 16; m <= 32; m <<= 1) {
        acc.x += __shfl_xor(acc.x, m, 64);
        acc.y += __shfl_xor(acc.y, m, 64);
        acc.z += __shfl_xor(acc.z, m, 64);
        acc.w += __shfl_xor(acc.w, m, 64);
    }
    if (grp == 0) {
        float dn = dinv[node];
        float4 bv = ((const float4*)bias)[sub];
        float4 r;
        r.x = fmaxf(fmaf(dn, acc.x, bv.x), 0.f);
        r.y = fmaxf(fmaf(dn, acc.y, bv.y), 0.f);
        r.z = fmaxf(fmaf(dn, acc.z, bv.z), 0.f);
        r.w = fmaxf(fmaf(dn, acc.w, bv.w), 0.f);
        ((float4*)H)[(size_t)node * 16 + sub] = r;
    }
}

// wave = 1 graph; binary search sorted batch for [start,end), mean over rows.
__global__ __launch_bounds__(256) void pool_kernel(const float* __restrict__ H,
                                                   const int* __restrict__ batch,
                                                   float* __restrict__ pooled,
                                                   int N, int NG) {
    int g = blockIdx.x * 4 + (threadIdx.x >> 6);
    if (g >= NG) return;
    g = __builtin_amdgcn_readfirstlane(g);
    int lane = threadIdx.x & 63;
    int grp = lane >> 4, sub = lane & 15;

    int lo = 0, hi = N;
    while (lo < hi) { int m = (lo + hi) >> 1; if (batch[m] < g) lo = m + 1; else hi = m; }
    int start = lo;
    int lo2 = start, hi2 = N;
    while (lo2 < hi2) { int m = (lo2 + hi2) >> 1; if (batch[m] < g + 1) lo2 = m + 1; else hi2 = m; }
    int end = lo2;

    const float4* H4 = (const float4*)H;
    float4 acc = make_float4(0.f, 0.f, 0.f, 0.f);
    for (int n = start + grp; n < end; n += 4) {
        float4 v = H4[(size_t)n * 16 + sub];
        acc.x += v.x; acc.y += v.y; acc.z += v.z; acc.w += v.w;
    }
#pragma unroll
    for (int m = 16; m <= 32; m <<= 1) {
        acc.x += __shfl_xor(acc.x, m, 64);
        acc.y += __shfl_xor(acc.y, m, 64);
        acc.z += __shfl_xor(acc.z, m, 64);
        acc.w += __shfl_xor(acc.w, m, 64);
    }
    if (grp == 0) {
        float inv = 1.0f / fmaxf((float)(end - start), 1.0f);
        float4 r;
        r.x = acc.x * inv; r.y = acc.y * inv; r.z = acc.z * inv; r.w = acc.w * inv;
        ((float4*)pooled)[(size_t)g * 16 + sub] = r;
    }
}

// per graph: z = relu(pooled@Wc1+bc1); out = z@Wc2+bc2
__global__ __launch_bounds__(64) void classifier(const float* __restrict__ pooled,
                                                 const float* __restrict__ Wc1,
                                                 const float* __restrict__ bc1,
                                                 const float* __restrict__ Wc2,
                                                 const float* __restrict__ bc2,
                                                 float* __restrict__ out) {
    int g = blockIdx.x;
    int t = threadIdx.x;
    __shared__ float p[64];
    __shared__ float z[32];
    p[t] = pooled[(size_t)g * 64 + t];
    __syncthreads();
    if (t < 32) {
        float a = bc1[t];
        for (int f = 0; f < 64; f++) a = fmaf(p[f], Wc1[f * 32 + t], a);
        z[t] = fmaxf(a, 0.f);
    }
    __syncthreads();
    if (t < 10) {
        float a = bc2[t];
        for (int j = 0; j < 32; j++) a = fmaf(z[j], Wc2[j * 10 + t], a);
        out[(size_t)g * 10 + t] = a;
    }
}

extern "C" void kernel_launch(void* const* d_in, const int* in_sizes, int n_in,
                              void* d_out, int out_size, void* d_ws, size_t ws_size,
                              hipStream_t stream) {
    const float* x   = (const float*)d_in[0];
    const int*   ei  = (const int*)d_in[1];
    const int*   bat = (const int*)d_in[2];
    const float* W1  = (const float*)d_in[3];
    const float* b1  = (const float*)d_in[4];
    const float* W2  = (const float*)d_in[5];
    const float* b2  = (const float*)d_in[6];
    const float* W3  = (const float*)d_in[7];
    const float* b3  = (const float*)d_in[8];
    const float* Wc1 = (const float*)d_in[9];
    const float* bc1 = (const float*)d_in[10];
    const float* Wc2 = (const float*)d_in[11];
    const float* bc2 = (const float*)d_in[12];

    const int N  = in_sizes[0] / 128;
    const int E  = in_sizes[1] / 2;
    const int NG = out_size / 10;
    const int* srcp = ei;
    const int* dstp = ei + E;

    char* ws = (char*)d_ws;
    size_t off = 0;
    auto alloc = [&](size_t bytes) -> void* {
        void* p = ws + off;
        off += (bytes + 255) / 256 * 256;
        return p;
    };
    float* G      = (float*)alloc((size_t)N * 64 * 4);
    float* H      = (float*)alloc((size_t)N * 64 * 4);
    int*   csr    = (int*)alloc((size_t)E * 4);
    int*   rp     = (int*)alloc((size_t)(N + 1) * 4);
    int*   cnt    = (int*)alloc((size_t)N * 4);
    int*   cursor = (int*)alloc((size_t)N * 4);
    float* dinv   = (float*)alloc((size_t)N * 4);
    int*   bs     = (int*)alloc(64 * 4);
    float* pooled = (float*)alloc((size_t)NG * 64 * 4);
    (void)ws_size; (void)n_in;

    const int NB = (N + 2047) / 2048;

    hipMemsetAsync(cnt, 0, (size_t)N * 4, stream);
    count_kernel<<<(E + 1023) / 1024, 256, 0, stream>>>(dstp, cnt, E);
    dinv_kernel<<<(N + 255) / 256, 256, 0, stream>>>(cnt, dinv, N);
    scanA<<<NB, 256, 0, stream>>>(cnt, rp, bs, N);
    scanB<<<1, 64, 0, stream>>>(bs, rp, NB, N);
    scanC<<<NB, 256, 0, stream>>>(rp, bs, N);
    hipMemcpyAsync(cursor, rp, (size_t)N * 4, hipMemcpyDeviceToDevice, stream);
    fill_kernel<<<(E + 1023) / 1024, 256, 0, stream>>>(srcp, dstp, cursor, csr, E);

    gemm_dinv<128, 4><<<(N + 15) / 16, 256, 0, stream>>>(x, W1, dinv, G, N);
    aggregate<<<(N + 3) / 4, 256, 0, stream>>>(G, rp, csr, dinv, b1, H, N);
    gemm_dinv<64, 8><<<(N + 31) / 32, 256, 0, stream>>>(H, W2, dinv, G, N);
    aggregate<<<(N + 3) / 4, 256, 0, stream>>>(G, rp, csr, dinv, b2, H, N);
    gemm_dinv<64, 8><<<(N + 31) / 32, 256, 0, stream>>>(H, W3, dinv, G, N);
    aggregate<<<(N + 3) / 4, 256, 0, stream>>>(G, rp, csr, dinv, b3, H, N);

    pool_kernel<<<(NG + 3) / 4, 256, 0, stream>>>(H, bat, pooled, N, NG);
    classifier<<<NG, 64, 0, stream>>>(pooled, Wc1, bc1, Wc2, bc2, (float*)d_out);
}

// Round 4
// 1146.047 us; speedup vs baseline: 2.1169x; 2.1169x over previous
//
#include <hip/hip_runtime.h>
#include <hip/hip_bf16.h>

// GCN forward: CSR-by-dst build once, then 3x (GEMM -> gather-aggregate -> ReLU),
// binary-search mean-pool, MLP classifier.
// norm = dinv[src]*dinv[dst] factored: dinv[src] into GEMM epilogue,
// dinv[dst]+bias+relu into aggregate epilogue. Self-loop = accumulator init.

__global__ void count_kernel(const int* __restrict__ dst, int* __restrict__ cnt, int E) {
    int i = blockIdx.x * 256 + threadIdx.x;
    int e = i * 4;
    if (e + 4 <= E) {
        int4 d = ((const int4*)dst)[i];
        atomicAdd(&cnt[d.x], 1);
        atomicAdd(&cnt[d.y], 1);
        atomicAdd(&cnt[d.z], 1);
        atomicAdd(&cnt[d.w], 1);
    } else {
        for (; e < E; e++) atomicAdd(&cnt[dst[e]], 1);
    }
}

__global__ void dinv_kernel(const int* __restrict__ cnt, float* __restrict__ dinv, int N) {
    int i = blockIdx.x * 256 + threadIdx.x;
    if (i < N) dinv[i] = rsqrtf((float)(cnt[i] + 1));  // +1 = self loop
}

// exclusive scan, 2048 elems/block
__global__ void scanA(const int* __restrict__ cnt, int* __restrict__ rp,
                      int* __restrict__ bs, int N) {
    __shared__ int lds[256];
    int t = threadIdx.x;
    int base = blockIdx.x * 2048 + t * 8;
    int v[8]; int tsum = 0;
#pragma unroll
    for (int i = 0; i < 8; i++) { int idx = base + i; int x = (idx < N) ? cnt[idx] : 0; v[i] = x; tsum += x; }
    lds[t] = tsum; __syncthreads();
#pragma unroll
    for (int d = 1; d < 256; d <<= 1) {
        int x = (t >= d) ? lds[t - d] : 0; __syncthreads();
        lds[t] += x; __syncthreads();
    }
    int run = lds[t] - tsum;
#pragma unroll
    for (int i = 0; i < 8; i++) { int idx = base + i; if (idx < N) rp[idx] = run; run += v[i]; }
    if (t == 255) bs[blockIdx.x] = lds[255];
}

__global__ void scanB(int* bs, int* rp, int NB, int N) {
    if (threadIdx.x == 0 && blockIdx.x == 0) {
        int run = 0;
        for (int i = 0; i < NB; i++) { int x = bs[i]; bs[i] = run; run += x; }
        rp[N] = run;
    }
}

__global__ void scanC(int* __restrict__ rp, const int* __restrict__ bs, int N) {
    int base = blockIdx.x * 2048 + threadIdx.x * 8;
    int add = bs[blockIdx.x];
#pragma unroll
    for (int i = 0; i < 8; i++) { int j = base + i; if (j < N) rp[j] += add; }
}

// cursor pre-filled with rp via d2d copy: pos = atomicAdd(&cursor[d],1)
__global__ void fill_kernel(const int* __restrict__ src, const int* __restrict__ dst,
                            int* __restrict__ cursor, int* __restrict__ csr, int E) {
    int i = blockIdx.x * 256 + threadIdx.x;
    int e = i * 4;
    if (e + 4 <= E) {
        int4 d = ((const int4*)dst)[i];
        int4 s = ((const int4*)src)[i];
        int p0 = atomicAdd(&cursor[d.x], 1);
        int p1 = atomicAdd(&cursor[d.y], 1);
        int p2 = atomicAdd(&cursor[d.z], 1);
        int p3 = atomicAdd(&cursor[d.w], 1);
        csr[p0] = s.x; csr[p1] = s.y; csr[p2] = s.z; csr[p3] = s.w;
    } else {
        for (; e < E; e++) {
            int d = dst[e];
            int pos = atomicAdd(&cursor[d], 1);
            csr[pos] = src[e];
        }
    }
}

// G[row][j] = dinv[row] * sum_k X[row][k]*W[k][j]
// lane j owns output column j. W held in VGPRs in chunks of KC (no spill!);
// X tile staged in LDS, read back as wave-uniform float4 broadcasts.
template <int K, int RPW, int KC>
__global__ __launch_bounds__(256) void gemm_dinv(const float* __restrict__ X,
                                                 const float* __restrict__ W,
                                                 const float* __restrict__ dinv,
                                                 float* __restrict__ G, int N) {
    constexpr int ROWS = 4 * RPW;
    __shared__ float Xl[ROWS * K];
    int lane = threadIdx.x & 63;
    int wid  = threadIdx.x >> 6;
    int row0 = blockIdx.x * ROWS;
    const float* xsrc = X + (size_t)row0 * K;

    if (row0 + ROWS <= N) {
#pragma unroll
        for (int i = threadIdx.x; i < ROWS * K / 4; i += 256)
            ((float4*)Xl)[i] = ((const float4*)xsrc)[i];
    } else {
        int avail = (N - row0) * K;
        for (int i = threadIdx.x; i < ROWS * K; i += 256)
            Xl[i] = (i < avail) ? xsrc[i] : 0.f;
    }
    __syncthreads();

    float acc[RPW];
#pragma unroll
    for (int r = 0; r < RPW; r++) acc[r] = 0.f;
    int rbase = wid * RPW;

#pragma unroll 1  // keep chunks sequential so only one w[KC] is live (NO spill)
    for (int c = 0; c < K / KC; c++) {
        float w[KC];
#pragma unroll
        for (int k = 0; k < KC; k++) w[k] = W[(c * KC + k) * 64 + lane];
#pragma unroll
        for (int r = 0; r < RPW; r++) {
            const float* xrow = &Xl[(rbase + r) * K + c * KC];
#pragma unroll
            for (int k4 = 0; k4 < KC / 4; k4++) {
                float4 xv = *(const float4*)&xrow[k4 * 4];  // wave-uniform broadcast
                acc[r] = fmaf(xv.x, w[k4 * 4 + 0], acc[r]);
                acc[r] = fmaf(xv.y, w[k4 * 4 + 1], acc[r]);
                acc[r] = fmaf(xv.z, w[k4 * 4 + 2], acc[r]);
                acc[r] = fmaf(xv.w, w[k4 * 4 + 3], acc[r]);
            }
        }
    }
#pragma unroll
    for (int r = 0; r < RPW; r++) {
        int row = row0 + rbase + r;
        if (row < N) G[(size_t)row * 64 + lane] = dinv[row] * acc[r];
    }
}

// H[node] = relu(dinv[node] * (G[node] + sum_{src} G[src]) + b)
// wave = 1 node; 4 groups x 16 lanes, each group handles one edge via float4.
__global__ __launch_bounds__(256) void aggregate(const float* __restrict__ G,
                                                 const int* __restrict__ rp,
                                                 const int* __restrict__ csr,
                                                 const float* __restrict__ dinv,
                                                 const float* __restrict__ bias,
                                                 float* __restrict__ H, int N) {
    int node = blockIdx.x * 4 + (threadIdx.x >> 6);
    if (node >= N) return;
    node = __builtin_amdgcn_readfirstlane(node);
    int lane = threadIdx.x & 63;
    int grp = lane >> 4, sub = lane & 15;
    int beg = rp[node], end = rp[node + 1];
    const float4* G4 = (const float4*)G;

    float4 acc = make_float4(0.f, 0.f, 0.f, 0.f);
    if (grp == 0) acc = G4[(size_t)node * 16 + sub];  // self loop

    int e = beg + grp;
    for (; e + 4 < end; e += 8) {
        int s0 = csr[e], s1 = csr[e + 4];
        float4 v0 = G4[(size_t)s0 * 16 + sub];
        float4 v1 = G4[(size_t)s1 * 16 + sub];
        acc.x += v0.x; acc.y += v0.y; acc.z += v0.z; acc.w += v0.w;
        acc.x += v1.x; acc.y += v1.y; acc.z += v1.z; acc.w += v1.w;
    }
    if (e < end) {
        int s0 = csr[e];
        float4 v0 = G4[(size_t)s0 * 16 + sub];
        acc.x += v0.x; acc.y += v0.y; acc.z += v0.z; acc.w += v0.w;
    }
#pragma unroll
    for (int m = 16; m <= 32; m <<= 1) {
        acc.x += __shfl_xor(acc.x, m, 64);
        acc.y += __shfl_xor(acc.y, m, 64);
        acc.z += __shfl_xor(acc.z, m, 64);
        acc.w += __shfl_xor(acc.w, m, 64);
    }
    if (grp == 0) {
        float dn = dinv[node];
        float4 bv = ((const float4*)bias)[sub];
        float4 r;
        r.x = fmaxf(fmaf(dn, acc.x, bv.x), 0.f);
        r.y = fmaxf(fmaf(dn, acc.y, bv.y), 0.f);
        r.z = fmaxf(fmaf(dn, acc.z, bv.z), 0.f);
        r.w = fmaxf(fmaf(dn, acc.w, bv.w), 0.f);
        ((float4*)H)[(size_t)node * 16 + sub] = r;
    }
}

// wave = 1 graph; binary search sorted batch for [start,end), mean over rows.
__global__ __launch_bounds__(256) void pool_kernel(const float* __restrict__ H,
                                                   const int* __restrict__ batch,
                                                   float* __restrict__ pooled,
                                                   int N, int NG) {
    int g = blockIdx.x * 4 + (threadIdx.x >> 6);
    if (g >= NG) return;
    g = __builtin_amdgcn_readfirstlane(g);
    int lane = threadIdx.x & 63;
    int grp = lane >> 4, sub = lane & 15;

    int lo = 0, hi = N;
    while (lo < hi) { int m = (lo + hi) >> 1; if (batch[m] < g) lo = m + 1; else hi = m; }
    int start = lo;
    int lo2 = start, hi2 = N;
    while (lo2 < hi2) { int m = (lo2 + hi2) >> 1; if (batch[m] < g + 1) lo2 = m + 1; else hi2 = m; }
    int end = lo2;

    const float4* H4 = (const float4*)H;
    float4 acc = make_float4(0.f, 0.f, 0.f, 0.f);
    for (int n = start + grp; n < end; n += 4) {
        float4 v = H4[(size_t)n * 16 + sub];
        acc.x += v.x; acc.y += v.y; acc.z += v.z; acc.w += v.w;
    }
#pragma unroll
    for (int m = 16; m <= 32; m <<= 1) {
        acc.x += __shfl_xor(acc.x, m, 64);
        acc.y += __shfl_xor(acc.y, m, 64);
        acc.z += __shfl_xor(acc.z, m, 64);
        acc.w += __shfl_xor(acc.w, m, 64);
    }
    if (grp == 0) {
        float inv = 1.0f / fmaxf((float)(end - start), 1.0f);
        float4 r;
        r.x = acc.x * inv; r.y = acc.y * inv; r.z = acc.z * inv; r.w = acc.w * inv;
        ((float4*)pooled)[(size_t)g * 16 + sub] = r;
    }
}

// per graph: z = relu(pooled@Wc1+bc1); out = z@Wc2+bc2
__global__ __launch_bounds__(64) void classifier(const float* __restrict__ pooled,
                                                 const float* __restrict__ Wc1,
                                                 const float* __restrict__ bc1,
                                                 const float* __restrict__ Wc2,
                                                 const float* __restrict__ bc2,
                                                 float* __restrict__ out) {
    int g = blockIdx.x;
    int t = threadIdx.x;
    __shared__ float p[64];
    __shared__ float z[32];
    p[t] = pooled[(size_t)g * 64 + t];
    __syncthreads();
    if (t < 32) {
        float a = bc1[t];
        for (int f = 0; f < 64; f++) a = fmaf(p[f], Wc1[f * 32 + t], a);
        z[t] = fmaxf(a, 0.f);
    }
    __syncthreads();
    if (t < 10) {
        float a = bc2[t];
        for (int j = 0; j < 32; j++) a = fmaf(z[j], Wc2[j * 10 + t], a);
        out[(size_t)g * 10 + t] = a;
    }
}

extern "C" void kernel_launch(void* const* d_in, const int* in_sizes, int n_in,
                              void* d_out, int out_size, void* d_ws, size_t ws_size,
                              hipStream_t stream) {
    const float* x   = (const float*)d_in[0];
    const int*   ei  = (const int*)d_in[1];
    const int*   bat = (const int*)d_in[2];
    const float* W1  = (const float*)d_in[3];
    const float* b1  = (const float*)d_in[4];
    const float* W2  = (const float*)d_in[5];
    const float* b2  = (const float*)d_in[6];
    const float* W3  = (const float*)d_in[7];
    const float* b3  = (const float*)d_in[8];
    const float* Wc1 = (const float*)d_in[9];
    const float* bc1 = (const float*)d_in[10];
    const float* Wc2 = (const float*)d_in[11];
    const float* bc2 = (const float*)d_in[12];

    const int N  = in_sizes[0] / 128;
    const int E  = in_sizes[1] / 2;
    const int NG = out_size / 10;
    const int* srcp = ei;
    const int* dstp = ei + E;

    char* ws = (char*)d_ws;
    size_t off = 0;
    auto alloc = [&](size_t bytes) -> void* {
        void* p = ws + off;
        off += (bytes + 255) / 256 * 256;
        return p;
    };
    float* G      = (float*)alloc((size_t)N * 64 * 4);
    float* H      = (float*)alloc((size_t)N * 64 * 4);
    int*   csr    = (int*)alloc((size_t)E * 4);
    int*   rp     = (int*)alloc((size_t)(N + 1) * 4);
    int*   cnt    = (int*)alloc((size_t)N * 4);
    int*   cursor = (int*)alloc((size_t)N * 4);
    float* dinv   = (float*)alloc((size_t)N * 4);
    int*   bs     = (int*)alloc(64 * 4);
    float* pooled = (float*)alloc((size_t)NG * 64 * 4);
    (void)ws_size; (void)n_in;

    const int NB = (N + 2047) / 2048;

    hipMemsetAsync(cnt, 0, (size_t)N * 4, stream);
    count_kernel<<<(E + 1023) / 1024, 256, 0, stream>>>(dstp, cnt, E);
    dinv_kernel<<<(N + 255) / 256, 256, 0, stream>>>(cnt, dinv, N);
    scanA<<<NB, 256, 0, stream>>>(cnt, rp, bs, N);
    scanB<<<1, 64, 0, stream>>>(bs, rp, NB, N);
    scanC<<<NB, 256, 0, stream>>>(rp, bs, N);
    hipMemcpyAsync(cursor, rp, (size_t)N * 4, hipMemcpyDeviceToDevice, stream);
    fill_kernel<<<(E + 1023) / 1024, 256, 0, stream>>>(srcp, dstp, cursor, csr, E);

    // 32 rows/block, 8 rows/wave; W in 64-reg chunks
    gemm_dinv<128, 8, 64><<<(N + 31) / 32, 256, 0, stream>>>(x, W1, dinv, G, N);
    aggregate<<<(N + 3) / 4, 256, 0, stream>>>(G, rp, csr, dinv, b1, H, N);
    gemm_dinv<64, 8, 64><<<(N + 31) / 32, 256, 0, stream>>>(H, W2, dinv, G, N);
    aggregate<<<(N + 3) / 4, 256, 0, stream>>>(G, rp, csr, dinv, b2, H, N);
    gemm_dinv<64, 8, 64><<<(N + 31) / 32, 256, 0, stream>>>(H, W3, dinv, G, N);
    aggregate<<<(N + 3) / 4, 256, 0, stream>>>(G, rp, csr, dinv, b3, H, N);

    pool_kernel<<<(NG + 3) / 4, 256, 0, stream>>>(H, bat, pooled, N, NG);
    classifier<<<NG, 64, 0, stream>>>(pooled, Wc1, bc1, Wc2, bc2, (float*)d_out);
}

// Round 5
// 1128.238 us; speedup vs baseline: 2.1503x; 1.0158x over previous
//
#include <hip/hip_runtime.h>
#include <hip/hip_bf16.h>

// GCN forward: CSR-by-dst build once, then 3x (GEMM -> gather-aggregate -> ReLU),
// binary-search mean-pool, MLP classifier.
// norm = dinv[src]*dinv[dst] factored: dinv[src] into GEMM epilogue,
// dinv[dst]+bias+relu into aggregate epilogue. Self-loop = accumulator init.
// fill/count: 1 edge/thread (3.2M threads = deep TLP to hide atomic latency;
// 4-edge/thread variant measured WORSE: 300 vs 180 us).

__global__ void count_kernel(const int* __restrict__ dst, int* __restrict__ cnt, int E) {
    int e = blockIdx.x * 256 + threadIdx.x;
    if (e < E) atomicAdd(&cnt[dst[e]], 1);
}

__global__ void dinv_kernel(const int* __restrict__ cnt, float* __restrict__ dinv, int N) {
    int i = blockIdx.x * 256 + threadIdx.x;
    if (i < N) dinv[i] = rsqrtf((float)(cnt[i] + 1));  // +1 = self loop
}

// exclusive scan, 2048 elems/block
__global__ void scanA(const int* __restrict__ cnt, int* __restrict__ rp,
                      int* __restrict__ bs, int N) {
    __shared__ int lds[256];
    int t = threadIdx.x;
    int base = blockIdx.x * 2048 + t * 8;
    int v[8]; int tsum = 0;
#pragma unroll
    for (int i = 0; i < 8; i++) { int idx = base + i; int x = (idx < N) ? cnt[idx] : 0; v[i] = x; tsum += x; }
    lds[t] = tsum; __syncthreads();
#pragma unroll
    for (int d = 1; d < 256; d <<= 1) {
        int x = (t >= d) ? lds[t - d] : 0; __syncthreads();
        lds[t] += x; __syncthreads();
    }
    int run = lds[t] - tsum;
#pragma unroll
    for (int i = 0; i < 8; i++) { int idx = base + i; if (idx < N) rp[idx] = run; run += v[i]; }
    if (t == 255) bs[blockIdx.x] = lds[255];
}

__global__ void scanB(int* bs, int* rp, int NB, int N) {
    if (threadIdx.x == 0 && blockIdx.x == 0) {
        int run = 0;
        for (int i = 0; i < NB; i++) { int x = bs[i]; bs[i] = run; run += x; }
        rp[N] = run;
    }
}

__global__ void scanC(int* __restrict__ rp, const int* __restrict__ bs, int N) {
    int base = blockIdx.x * 2048 + threadIdx.x * 8;
    int add = bs[blockIdx.x];
#pragma unroll
    for (int i = 0; i < 8; i++) { int j = base + i; if (j < N) rp[j] += add; }
}

// cursor pre-filled with rp via d2d copy: pos = atomicAdd(&cursor[d],1)
__global__ void fill_kernel(const int* __restrict__ src, const int* __restrict__ dst,
                            int* __restrict__ cursor, int* __restrict__ csr, int E) {
    int e = blockIdx.x * 256 + threadIdx.x;
    if (e < E) {
        int pos = atomicAdd(&cursor[dst[e]], 1);
        csr[pos] = src[e];
    }
}

// G[row][j] = dinv[row] * sum_k X[row][k]*W[k][j]
// lane j owns output column j. W held in VGPRs in chunks of KC (no spill);
// X tile staged in LDS, read back as wave-uniform float4 broadcasts.
template <int K, int RPW, int KC>
__global__ __launch_bounds__(256) void gemm_dinv(const float* __restrict__ X,
                                                 const float* __restrict__ W,
                                                 const float* __restrict__ dinv,
                                                 float* __restrict__ G, int N) {
    constexpr int ROWS = 4 * RPW;
    __shared__ float Xl[ROWS * K];
    int lane = threadIdx.x & 63;
    int wid  = threadIdx.x >> 6;
    int row0 = blockIdx.x * ROWS;
    const float* xsrc = X + (size_t)row0 * K;

    if (row0 + ROWS <= N) {
#pragma unroll
        for (int i = threadIdx.x; i < ROWS * K / 4; i += 256)
            ((float4*)Xl)[i] = ((const float4*)xsrc)[i];
    } else {
        int avail = (N - row0) * K;
        for (int i = threadIdx.x; i < ROWS * K; i += 256)
            Xl[i] = (i < avail) ? xsrc[i] : 0.f;
    }
    __syncthreads();

    float acc[RPW];
#pragma unroll
    for (int r = 0; r < RPW; r++) acc[r] = 0.f;
    int rbase = wid * RPW;

#pragma unroll 1  // chunks sequential: only one w[KC] live at a time (no spill)
    for (int c = 0; c < K / KC; c++) {
        float w[KC];
#pragma unroll
        for (int k = 0; k < KC; k++) w[k] = W[(c * KC + k) * 64 + lane];
#pragma unroll
        for (int r = 0; r < RPW; r++) {
            const float* xrow = &Xl[(rbase + r) * K + c * KC];
#pragma unroll
            for (int k4 = 0; k4 < KC / 4; k4++) {
                float4 xv = *(const float4*)&xrow[k4 * 4];  // wave-uniform broadcast
                acc[r] = fmaf(xv.x, w[k4 * 4 + 0], acc[r]);
                acc[r] = fmaf(xv.y, w[k4 * 4 + 1], acc[r]);
                acc[r] = fmaf(xv.z, w[k4 * 4 + 2], acc[r]);
                acc[r] = fmaf(xv.w, w[k4 * 4 + 3], acc[r]);
            }
        }
    }
#pragma unroll
    for (int r = 0; r < RPW; r++) {
        int row = row0 + rbase + r;
        if (row < N) G[(size_t)row * 64 + lane] = dinv[row] * acc[r];
    }
}

// H[node] = relu(dinv[node] * (G[node] + sum_{src} G[src]) + b)
// wave = 1 node; 4 groups x 16 lanes; 4 edges in flight per group (ILP).
__global__ __launch_bounds__(256) void aggregate(const float* __restrict__ G,
                                                 const int* __restrict__ rp,
                                                 const int* __restrict__ csr,
                                                 const float* __restrict__ dinv,
                                                 const float* __restrict__ bias,
                                                 float* __restrict__ H, int N) {
    int node = blockIdx.x * 4 + (threadIdx.x >> 6);
    if (node >= N) return;
    node = __builtin_amdgcn_readfirstlane(node);
    int lane = threadIdx.x & 63;
    int grp = lane >> 4, sub = lane & 15;
    int beg = rp[node], end = rp[node + 1];
    const float4* G4 = (const float4*)G;

    float4 acc = make_float4(0.f, 0.f, 0.f, 0.f);
    if (grp == 0) acc = G4[(size_t)node * 16 + sub];  // self loop

    int e = beg + grp;
    for (; e + 12 < end; e += 16) {
        int s0 = csr[e], s1 = csr[e + 4], s2 = csr[e + 8], s3 = csr[e + 12];
        float4 v0 = G4[(size_t)s0 * 16 + sub];
        float4 v1 = G4[(size_t)s1 * 16 + sub];
        float4 v2 = G4[(size_t)s2 * 16 + sub];
        float4 v3 = G4[(size_t)s3 * 16 + sub];
        acc.x += v0.x; acc.y += v0.y; acc.z += v0.z; acc.w += v0.w;
        acc.x += v1.x; acc.y += v1.y; acc.z += v1.z; acc.w += v1.w;
        acc.x += v2.x; acc.y += v2.y; acc.z += v2.z; acc.w += v2.w;
        acc.x += v3.x; acc.y += v3.y; acc.z += v3.z; acc.w += v3.w;
    }
    for (; e < end; e += 4) {
        int s0 = csr[e];
        float4 v0 = G4[(size_t)s0 * 16 + sub];
        acc.x += v0.x; acc.y += v0.y; acc.z += v0.z; acc.w += v0.w;
    }
#pragma unroll
    for (int m = 16; m <= 32; m <<= 1) {
        acc.x += __shfl_xor(acc.x, m, 64);
        acc.y += __shfl_xor(acc.y, m, 64);
        acc.z += __shfl_xor(acc.z, m, 64);
        acc.w += __shfl_xor(acc.w, m, 64);
    }
    if (grp == 0) {
        float dn = dinv[node];
        float4 bv = ((const float4*)bias)[sub];
        float4 r;
        r.x = fmaxf(fmaf(dn, acc.x, bv.x), 0.f);
        r.y = fmaxf(fmaf(dn, acc.y, bv.y), 0.f);
        r.z = fmaxf(fmaf(dn, acc.z, bv.z), 0.f);
        r.w = fmaxf(fmaf(dn, acc.w, bv.w), 0.f);
        ((float4*)H)[(size_t)node * 16 + sub] = r;
    }
}

// wave = 1 graph; binary search sorted batch for [start,end), mean over rows.
__global__ __launch_bounds__(256) void pool_kernel(const float* __restrict__ H,
                                                   const int* __restrict__ batch,
                                                   float* __restrict__ pooled,
                                                   int N, int NG) {
    int g = blockIdx.x * 4 + (threadIdx.x >> 6);
    if (g >= NG) return;
    g = __builtin_amdgcn_readfirstlane(g);
    int lane = threadIdx.x & 63;
    int grp = lane >> 4, sub = lane & 15;

    int lo = 0, hi = N;
    while (lo < hi) { int m = (lo + hi) >> 1; if (batch[m] < g) lo = m + 1; else hi = m; }
    int start = lo;
    int lo2 = start, hi2 = N;
    while (lo2 < hi2) { int m = (lo2 + hi2) >> 1; if (batch[m] < g + 1) lo2 = m + 1; else hi2 = m; }
    int end = lo2;

    const float4* H4 = (const float4*)H;
    float4 acc = make_float4(0.f, 0.f, 0.f, 0.f);
    for (int n = start + grp; n < end; n += 4) {
        float4 v = H4[(size_t)n * 16 + sub];
        acc.x += v.x; acc.y += v.y; acc.z += v.z; acc.w += v.w;
    }
#pragma unroll
    for (int m = 16; m <= 32; m <<= 1) {
        acc.x += __shfl_xor(acc.x, m, 64);
        acc.y += __shfl_xor(acc.y, m, 64);
        acc.z += __shfl_xor(acc.z, m, 64);
        acc.w += __shfl_xor(acc.w, m, 64);
    }
    if (grp == 0) {
        float inv = 1.0f / fmaxf((float)(end - start), 1.0f);
        float4 r;
        r.x = acc.x * inv; r.y = acc.y * inv; r.z = acc.z * inv; r.w = acc.w * inv;
        ((float4*)pooled)[(size_t)g * 16 + sub] = r;
    }
}

// per graph: z = relu(pooled@Wc1+bc1); out = z@Wc2+bc2
__global__ __launch_bounds__(64) void classifier(const float* __restrict__ pooled,
                                                 const float* __restrict__ Wc1,
                                                 const float* __restrict__ bc1,
                                                 const float* __restrict__ Wc2,
                                                 const float* __restrict__ bc2,
                                                 float* __restrict__ out) {
    int g = blockIdx.x;
    int t = threadIdx.x;
    __shared__ float p[64];
    __shared__ float z[32];
    p[t] = pooled[(size_t)g * 64 + t];
    __syncthreads();
    if (t < 32) {
        float a = bc1[t];
        for (int f = 0; f < 64; f++) a = fmaf(p[f], Wc1[f * 32 + t], a);
        z[t] = fmaxf(a, 0.f);
    }
    __syncthreads();
    if (t < 10) {
        float a = bc2[t];
        for (int j = 0; j < 32; j++) a = fmaf(z[j], Wc2[j * 10 + t], a);
        out[(size_t)g * 10 + t] = a;
    }
}

extern "C" void kernel_launch(void* const* d_in, const int* in_sizes, int n_in,
                              void* d_out, int out_size, void* d_ws, size_t ws_size,
                              hipStream_t stream) {
    const float* x   = (const float*)d_in[0];
    const int*   ei  = (const int*)d_in[1];
    const int*   bat = (const int*)d_in[2];
    const float* W1  = (const float*)d_in[3];
    const float* b1  = (const float*)d_in[4];
    const float* W2  = (const float*)d_in[5];
    const float* b2  = (const float*)d_in[6];
    const float* W3  = (const float*)d_in[7];
    const float* b3  = (const float*)d_in[8];
    const float* Wc1 = (const float*)d_in[9];
    const float* bc1 = (const float*)d_in[10];
    const float* Wc2 = (const float*)d_in[11];
    const float* bc2 = (const float*)d_in[12];

    const int N  = in_sizes[0] / 128;
    const int E  = in_sizes[1] / 2;
    const int NG = out_size / 10;
    const int* srcp = ei;
    const int* dstp = ei + E;

    char* ws = (char*)d_ws;
    size_t off = 0;
    auto alloc = [&](size_t bytes) -> void* {
        void* p = ws + off;
        off += (bytes + 255) / 256 * 256;
        return p;
    };
    float* G      = (float*)alloc((size_t)N * 64 * 4);
    float* H      = (float*)alloc((size_t)N * 64 * 4);
    int*   csr    = (int*)alloc((size_t)E * 4);
    int*   rp     = (int*)alloc((size_t)(N + 1) * 4);
    int*   cnt    = (int*)alloc((size_t)N * 4);
    int*   cursor = (int*)alloc((size_t)N * 4);
    float* dinv   = (float*)alloc((size_t)N * 4);
    int*   bs     = (int*)alloc(64 * 4);
    float* pooled = (float*)alloc((size_t)NG * 64 * 4);
    (void)ws_size; (void)n_in;

    const int NB = (N + 2047) / 2048;

    hipMemsetAsync(cnt, 0, (size_t)N * 4, stream);
    count_kernel<<<(E + 255) / 256, 256, 0, stream>>>(dstp, cnt, E);
    dinv_kernel<<<(N + 255) / 256, 256, 0, stream>>>(cnt, dinv, N);
    scanA<<<NB, 256, 0, stream>>>(cnt, rp, bs, N);
    scanB<<<1, 64, 0, stream>>>(bs, rp, NB, N);
    scanC<<<NB, 256, 0, stream>>>(rp, bs, N);
    hipMemcpyAsync(cursor, rp, (size_t)N * 4, hipMemcpyDeviceToDevice, stream);
    fill_kernel<<<(E + 255) / 256, 256, 0, stream>>>(srcp, dstp, cursor, csr, E);

    // 32 rows/block, 8 rows/wave; W in 64-reg chunks
    gemm_dinv<128, 8, 64><<<(N + 31) / 32, 256, 0, stream>>>(x, W1, dinv, G, N);
    aggregate<<<(N + 3) / 4, 256, 0, stream>>>(G, rp, csr, dinv, b1, H, N);
    gemm_dinv<64, 8, 64><<<(N + 31) / 32, 256, 0, stream>>>(H, W2, dinv, G, N);
    aggregate<<<(N + 3) / 4, 256, 0, stream>>>(G, rp, csr, dinv, b2, H, N);
    gemm_dinv<64, 8, 64><<<(N + 31) / 32, 256, 0, stream>>>(H, W3, dinv, G, N);
    aggregate<<<(N + 3) / 4, 256, 0, stream>>>(G, rp, csr, dinv, b3, H, N);

    pool_kernel<<<(NG + 3) / 4, 256, 0, stream>>>(H, bat, pooled, N, NG);
    classifier<<<NG, 64, 0, stream>>>(pooled, Wc1, bc1, Wc2, bc2, (float*)d_out);
}

// Round 6
// 958.188 us; speedup vs baseline: 2.5319x; 1.1775x over previous
//
#include <hip/hip_runtime.h>
#include <hip/hip_bf16.h>

// GCN forward. CSR build via bucketed counting sort (dst>>6 buckets):
//   bucket_count (LDS-preagg) -> bucket_scan -> scatter (packed 4B entries into
//   hot per-bucket windows; L2 write-combining) -> csr_build (per-bucket block:
//   LDS hist -> rp/dinv/csr, single-XCD window writes).
// This replaces count/scan-over-N/fill, whose random 4B scatter wrote 195 MB
// (61B/entry cacheline amplification, 270 us measured).
// Then 3x (GEMM -> pull-aggregate -> ReLU), binary-search mean-pool, MLP.
// norm = dinv[src]*dinv[dst] factored into GEMM / aggregate epilogues.
// fill/count history: 1 edge/thread > 4 edges/thread (TLP hides atomic latency).

#define BMAX 2048  // buckets = ceil(N/64); N<=131072

__global__ __launch_bounds__(256) void bucket_count(const int* __restrict__ dst,
                                                    int* __restrict__ bcnt,
                                                    int E, int B, int chunk) {
    __shared__ int hist[BMAX];
    for (int i = threadIdx.x; i < BMAX; i += 256) hist[i] = 0;
    __syncthreads();
    int s = blockIdx.x * chunk;
    int en = min(s + chunk, E);
    for (int i = s + threadIdx.x; i < en; i += 256)
        atomicAdd(&hist[dst[i] >> 6], 1);
    __syncthreads();
    for (int i = threadIdx.x; i < B; i += 256) {
        int c = hist[i];
        if (c) atomicAdd(&bcnt[i], c);
    }
}

// single block: exclusive scan of bcnt[0..M) -> prp; also init padded cursors.
__global__ __launch_bounds__(256) void bucket_scan(const int* __restrict__ bcnt,
                                                   int* __restrict__ prp,
                                                   int* __restrict__ bcur, int M) {
    __shared__ int lds[256];
    int t = threadIdx.x;
    int base = t * 8;
    int v[8]; int ts = 0;
#pragma unroll
    for (int i = 0; i < 8; i++) { int idx = base + i; int x = (idx < M) ? bcnt[idx] : 0; v[i] = x; ts += x; }
    lds[t] = ts; __syncthreads();
#pragma unroll
    for (int d = 1; d < 256; d <<= 1) {
        int x = (t >= d) ? lds[t - d] : 0; __syncthreads();
        lds[t] += x; __syncthreads();
    }
    int run = lds[t] - ts;
#pragma unroll
    for (int i = 0; i < 8; i++) {
        int idx = base + i;
        if (idx < M) { prp[idx] = run; bcur[idx * 16] = run; run += v[i]; }
    }
    if (t == 255) prp[M] = lds[255];  // == E
}

// pairs[pos] = src | (dst&63)<<17  (src < 2^17); pos from per-bucket cursor.
__global__ void scatter_kernel(const int* __restrict__ src, const int* __restrict__ dst,
                               int* __restrict__ bcur, int* __restrict__ pairs, int E) {
    int e = blockIdx.x * 256 + threadIdx.x;
    if (e < E) {
        int d = dst[e];
        int pos = atomicAdd(&bcur[(d >> 6) * 16], 1);
        pairs[pos] = src[e] | ((d & 63) << 17);
    }
}

// one block per bucket: local hist -> rp, dinv, csr (writes land in the
// bucket's contiguous ~8KB windows -> combined in this XCD's L2).
__global__ __launch_bounds__(256) void csr_build(const int* __restrict__ pairs,
                                                 const int* __restrict__ prp,
                                                 int* __restrict__ rp,
                                                 float* __restrict__ dinv,
                                                 int* __restrict__ csr,
                                                 int N, int B, int E) {
    __shared__ int hist[64], cur[64];
    int b = blockIdx.x;
    int t = threadIdx.x;
    if (t < 64) hist[t] = 0;
    __syncthreads();
    int r0 = prp[b], r1 = prp[b + 1];
    for (int i = r0 + t; i < r1; i += 256)
        atomicAdd(&hist[pairs[i] >> 17], 1);
    __syncthreads();
    if (t == 0) {
        int run = r0;
        for (int k = 0; k < 64; k++) { cur[k] = run; run += hist[k]; }
    }
    __syncthreads();
    if (t < 64) {
        int node = b * 64 + t;
        if (node < N) {
            rp[node] = cur[t];
            dinv[node] = rsqrtf((float)(hist[t] + 1));  // +1 self loop
        }
    }
    if (b == B - 1 && t == 0) rp[N] = E;
    __syncthreads();
    for (int i = r0 + t; i < r1; i += 256) {
        int v = pairs[i];
        int pos = atomicAdd(&cur[v >> 17], 1);
        csr[pos] = v & 0x1FFFF;
    }
}

// G[row][j] = dinv[row] * sum_k X[row][k]*W[k][j]
// lane j owns output column j. W held in VGPRs in chunks of KC (no spill);
// X tile staged in LDS, read back as wave-uniform float4 broadcasts.
template <int K, int RPW, int KC>
__global__ __launch_bounds__(256) void gemm_dinv(const float* __restrict__ X,
                                                 const float* __restrict__ W,
                                                 const float* __restrict__ dinv,
                                                 float* __restrict__ G, int N) {
    constexpr int ROWS = 4 * RPW;
    __shared__ float Xl[ROWS * K];
    int lane = threadIdx.x & 63;
    int wid  = threadIdx.x >> 6;
    int row0 = blockIdx.x * ROWS;
    const float* xsrc = X + (size_t)row0 * K;

    if (row0 + ROWS <= N) {
#pragma unroll
        for (int i = threadIdx.x; i < ROWS * K / 4; i += 256)
            ((float4*)Xl)[i] = ((const float4*)xsrc)[i];
    } else {
        int avail = (N - row0) * K;
        for (int i = threadIdx.x; i < ROWS * K; i += 256)
            Xl[i] = (i < avail) ? xsrc[i] : 0.f;
    }
    __syncthreads();

    float acc[RPW];
#pragma unroll
    for (int r = 0; r < RPW; r++) acc[r] = 0.f;
    int rbase = wid * RPW;

#pragma unroll 1  // chunks sequential: only one w[KC] live at a time (no spill)
    for (int c = 0; c < K / KC; c++) {
        float w[KC];
#pragma unroll
        for (int k = 0; k < KC; k++) w[k] = W[(c * KC + k) * 64 + lane];
#pragma unroll
        for (int r = 0; r < RPW; r++) {
            const float* xrow = &Xl[(rbase + r) * K + c * KC];
#pragma unroll
            for (int k4 = 0; k4 < KC / 4; k4++) {
                float4 xv = *(const float4*)&xrow[k4 * 4];  // wave-uniform broadcast
                acc[r] = fmaf(xv.x, w[k4 * 4 + 0], acc[r]);
                acc[r] = fmaf(xv.y, w[k4 * 4 + 1], acc[r]);
                acc[r] = fmaf(xv.z, w[k4 * 4 + 2], acc[r]);
                acc[r] = fmaf(xv.w, w[k4 * 4 + 3], acc[r]);
            }
        }
    }
#pragma unroll
    for (int r = 0; r < RPW; r++) {
        int row = row0 + rbase + r;
        if (row < N) G[(size_t)row * 64 + lane] = dinv[row] * acc[r];
    }
}

// H[node] = relu(dinv[node] * (G[node] + sum_{src} G[src]) + b)
// wave = 1 node; 4 groups x 16 lanes; 4 edges in flight per group (ILP).
__global__ __launch_bounds__(256) void aggregate(const float* __restrict__ G,
                                                 const int* __restrict__ rp,
                                                 const int* __restrict__ csr,
                                                 const float* __restrict__ dinv,
                                                 const float* __restrict__ bias,
                                                 float* __restrict__ H, int N) {
    int node = blockIdx.x * 4 + (threadIdx.x >> 6);
    if (node >= N) return;
    node = __builtin_amdgcn_readfirstlane(node);
    int lane = threadIdx.x & 63;
    int grp = lane >> 4, sub = lane & 15;
    int beg = rp[node], end = rp[node + 1];
    const float4* G4 = (const float4*)G;

    float4 acc = make_float4(0.f, 0.f, 0.f, 0.f);
    if (grp == 0) acc = G4[(size_t)node * 16 + sub];  // self loop

    int e = beg + grp;
    for (; e + 12 < end; e += 16) {
        int s0 = csr[e], s1 = csr[e + 4], s2 = csr[e + 8], s3 = csr[e + 12];
        float4 v0 = G4[(size_t)s0 * 16 + sub];
        float4 v1 = G4[(size_t)s1 * 16 + sub];
        float4 v2 = G4[(size_t)s2 * 16 + sub];
        float4 v3 = G4[(size_t)s3 * 16 + sub];
        acc.x += v0.x; acc.y += v0.y; acc.z += v0.z; acc.w += v0.w;
        acc.x += v1.x; acc.y += v1.y; acc.z += v1.z; acc.w += v1.w;
        acc.x += v2.x; acc.y += v2.y; acc.z += v2.z; acc.w += v2.w;
        acc.x += v3.x; acc.y += v3.y; acc.z += v3.z; acc.w += v3.w;
    }
    for (; e < end; e += 4) {
        int s0 = csr[e];
        float4 v0 = G4[(size_t)s0 * 16 + sub];
        acc.x += v0.x; acc.y += v0.y; acc.z += v0.z; acc.w += v0.w;
    }
#pragma unroll
    for (int m = 16; m <= 32; m <<= 1) {
        acc.x += __shfl_xor(acc.x, m, 64);
        acc.y += __shfl_xor(acc.y, m, 64);
        acc.z += __shfl_xor(acc.z, m, 64);
        acc.w += __shfl_xor(acc.w, m, 64);
    }
    if (grp == 0) {
        float dn = dinv[node];
        float4 bv = ((const float4*)bias)[sub];
        float4 r;
        r.x = fmaxf(fmaf(dn, acc.x, bv.x), 0.f);
        r.y = fmaxf(fmaf(dn, acc.y, bv.y), 0.f);
        r.z = fmaxf(fmaf(dn, acc.z, bv.z), 0.f);
        r.w = fmaxf(fmaf(dn, acc.w, bv.w), 0.f);
        ((float4*)H)[(size_t)node * 16 + sub] = r;
    }
}

// wave = 1 graph; binary search sorted batch for [start,end), mean over rows.
__global__ __launch_bounds__(256) void pool_kernel(const float* __restrict__ H,
                                                   const int* __restrict__ batch,
                                                   float* __restrict__ pooled,
                                                   int N, int NG) {
    int g = blockIdx.x * 4 + (threadIdx.x >> 6);
    if (g >= NG) return;
    g = __builtin_amdgcn_readfirstlane(g);
    int lane = threadIdx.x & 63;
    int grp = lane >> 4, sub = lane & 15;

    int lo = 0, hi = N;
    while (lo < hi) { int m = (lo + hi) >> 1; if (batch[m] < g) lo = m + 1; else hi = m; }
    int start = lo;
    int lo2 = start, hi2 = N;
    while (lo2 < hi2) { int m = (lo2 + hi2) >> 1; if (batch[m] < g + 1) lo2 = m + 1; else hi2 = m; }
    int end = lo2;

    const float4* H4 = (const float4*)H;
    float4 acc = make_float4(0.f, 0.f, 0.f, 0.f);
    for (int n = start + grp; n < end; n += 4) {
        float4 v = H4[(size_t)n * 16 + sub];
        acc.x += v.x; acc.y += v.y; acc.z += v.z; acc.w += v.w;
    }
#pragma unroll
    for (int m = 16; m <= 32; m <<= 1) {
        acc.x += __shfl_xor(acc.x, m, 64);
        acc.y += __shfl_xor(acc.y, m, 64);
        acc.z += __shfl_xor(acc.z, m, 64);
        acc.w += __shfl_xor(acc.w, m, 64);
    }
    if (grp == 0) {
        float inv = 1.0f / fmaxf((float)(end - start), 1.0f);
        float4 r;
        r.x = acc.x * inv; r.y = acc.y * inv; r.z = acc.z * inv; r.w = acc.w * inv;
        ((float4*)pooled)[(size_t)g * 16 + sub] = r;
    }
}

// per graph: z = relu(pooled@Wc1+bc1); out = z@Wc2+bc2
__global__ __launch_bounds__(64) void classifier(const float* __restrict__ pooled,
                                                 const float* __restrict__ Wc1,
                                                 const float* __restrict__ bc1,
                                                 const float* __restrict__ Wc2,
                                                 const float* __restrict__ bc2,
                                                 float* __restrict__ out) {
    int g = blockIdx.x;
    int t = threadIdx.x;
    __shared__ float p[64];
    __shared__ float z[32];
    p[t] = pooled[(size_t)g * 64 + t];
    __syncthreads();
    if (t < 32) {
        float a = bc1[t];
        for (int f = 0; f < 64; f++) a = fmaf(p[f], Wc1[f * 32 + t], a);
        z[t] = fmaxf(a, 0.f);
    }
    __syncthreads();
    if (t < 10) {
        float a = bc2[t];
        for (int j = 0; j < 32; j++) a = fmaf(z[j], Wc2[j * 10 + t], a);
        out[(size_t)g * 10 + t] = a;
    }
}

extern "C" void kernel_launch(void* const* d_in, const int* in_sizes, int n_in,
                              void* d_out, int out_size, void* d_ws, size_t ws_size,
                              hipStream_t stream) {
    const float* x   = (const float*)d_in[0];
    const int*   ei  = (const int*)d_in[1];
    const int*   bat = (const int*)d_in[2];
    const float* W1  = (const float*)d_in[3];
    const float* b1  = (const float*)d_in[4];
    const float* W2  = (const float*)d_in[5];
    const float* b2  = (const float*)d_in[6];
    const float* W3  = (const float*)d_in[7];
    const float* b3  = (const float*)d_in[8];
    const float* Wc1 = (const float*)d_in[9];
    const float* bc1 = (const float*)d_in[10];
    const float* Wc2 = (const float*)d_in[11];
    const float* bc2 = (const float*)d_in[12];

    const int N  = in_sizes[0] / 128;
    const int E  = in_sizes[1] / 2;
    const int NG = out_size / 10;
    const int B  = (N + 63) >> 6;  // <= BMAX for N <= 131072
    const int* srcp = ei;
    const int* dstp = ei + E;

    char* ws = (char*)d_ws;
    size_t off = 0;
    auto alloc = [&](size_t bytes) -> void* {
        void* p = ws + off;
        off += (bytes + 255) / 256 * 256;
        return p;
    };
    float* G      = (float*)alloc((size_t)N * 64 * 4);
    float* H      = (float*)alloc((size_t)N * 64 * 4);
    int*   pairs  = (int*)H;  // alias: pairs (E ints) dead before first aggregate writes H
    int*   csr    = (int*)alloc((size_t)E * 4);
    int*   rp     = (int*)alloc((size_t)(N + 1) * 4);
    float* dinv   = (float*)alloc((size_t)N * 4);
    int*   bcnt   = (int*)alloc((size_t)BMAX * 4);
    int*   prp    = (int*)alloc((size_t)(BMAX + 1) * 4);
    int*   bcur   = (int*)alloc((size_t)BMAX * 16 * 4);  // 64B-padded cursors
    float* pooled = (float*)alloc((size_t)NG * 64 * 4);
    (void)ws_size; (void)n_in;

    // --- CSR build (bucketed counting sort) ---
    hipMemsetAsync(bcnt, 0, (size_t)B * 4, stream);
    int chunk = (E + 255) / 256;
    bucket_count<<<256, 256, 0, stream>>>(dstp, bcnt, E, B, chunk);
    bucket_scan<<<1, 256, 0, stream>>>(bcnt, prp, bcur, B);
    scatter_kernel<<<(E + 255) / 256, 256, 0, stream>>>(srcp, dstp, bcur, pairs, E);
    csr_build<<<B, 256, 0, stream>>>(pairs, prp, rp, dinv, csr, N, B, E);

    // --- 3 GCN layers: 32 rows/block GEMM (W in 64-reg chunks) + pull-aggregate ---
    gemm_dinv<128, 8, 64><<<(N + 31) / 32, 256, 0, stream>>>(x, W1, dinv, G, N);
    aggregate<<<(N + 3) / 4, 256, 0, stream>>>(G, rp, csr, dinv, b1, H, N);
    gemm_dinv<64, 8, 64><<<(N + 31) / 32, 256, 0, stream>>>(H, W2, dinv, G, N);
    aggregate<<<(N + 3) / 4, 256, 0, stream>>>(G, rp, csr, dinv, b2, H, N);
    gemm_dinv<64, 8, 64><<<(N + 31) / 32, 256, 0, stream>>>(H, W3, dinv, G, N);
    aggregate<<<(N + 3) / 4, 256, 0, stream>>>(G, rp, csr, dinv, b3, H, N);

    // --- pool + classifier ---
    pool_kernel<<<(NG + 3) / 4, 256, 0, stream>>>(H, bat, pooled, N, NG);
    classifier<<<NG, 64, 0, stream>>>(pooled, Wc1, bc1, Wc2, bc2, (float*)d_out);
}

// Round 7
// 804.843 us; speedup vs baseline: 3.0143x; 1.1905x over previous
//
#include <hip/hip_runtime.h>
#include <hip/hip_bf16.h>

// GCN forward. CSR build via two-level multisplit (radix-partition style):
//   part_hist (per-block LDS hist -> cntmat[bucket][block])
//   part_scan (wave/bucket shfl-scan over 256 block counts -> per-block excl
//              offsets in-place + bucket totals bcnt)
//   bucket_scan (bcnt -> prp bucket starts)
//   part_scatter (LDS cursors = prp[b]+cntmat[b][blk]; every output line is
//                 written by exactly ONE block/XCD -> write-combining works)
//   csr_build (per-bucket block: LDS hist -> rp/dinv/csr)
// History: naive 4B scatter wrote 195MB (61B/entry line amplification, 270us);
// shared-window bucketed scatter still 163MB/247us because windows were
// written by all XCDs concurrently (private L2s ping-pong the lines).
// Then 3x (GEMM -> pull-aggregate -> ReLU), binary-search mean-pool, MLP.
// norm = dinv[src]*dinv[dst] factored into GEMM / aggregate epilogues.

#define BMAX 2048  // buckets = ceil(N/64); N <= 131072
#define NBLK 256   // partition blocks (cntmat inner dim)

__global__ __launch_bounds__(1024) void part_hist(const int* __restrict__ dst,
                                                  int* __restrict__ cntmat,
                                                  int E, int B, int chunk) {
    __shared__ int hist[BMAX];
    for (int i = threadIdx.x; i < BMAX; i += 1024) hist[i] = 0;
    __syncthreads();
    int s = blockIdx.x * chunk;
    int en = min(s + chunk, E);
    for (int i = s + threadIdx.x; i < en; i += 1024)
        atomicAdd(&hist[dst[i] >> 6], 1);
    __syncthreads();
    for (int i = threadIdx.x; i < B; i += 1024)
        cntmat[i * NBLK + blockIdx.x] = hist[i];
}

// one wave per bucket: exclusive scan of cntmat[b][0..256) in 4x64 chunks.
__global__ __launch_bounds__(256) void part_scan(int* __restrict__ cntmat,
                                                 int* __restrict__ bcnt, int B) {
    int w = threadIdx.x >> 6;
    int lane = threadIdx.x & 63;
    int b = blockIdx.x * 4 + w;
    if (b >= B) return;
    int carry = 0;
#pragma unroll
    for (int j = 0; j < NBLK / 64; j++) {
        int idx = b * NBLK + j * 64 + lane;
        int v = cntmat[idx];
        int x = v;
#pragma unroll
        for (int d = 1; d < 64; d <<= 1) {
            int t = __shfl_up(x, d, 64);
            if (lane >= d) x += t;
        }
        cntmat[idx] = x - v + carry;          // exclusive within bucket
        carry += __shfl(x, 63, 64);           // add chunk total
    }
    if (lane == 0) bcnt[b] = carry;
}

// single block: exclusive scan of bcnt[0..M) -> prp (bucket starts).
__global__ __launch_bounds__(256) void bucket_scan(const int* __restrict__ bcnt,
                                                   int* __restrict__ prp, int M) {
    __shared__ int lds[256];
    int t = threadIdx.x;
    int base = t * 8;
    int v[8]; int ts = 0;
#pragma unroll
    for (int i = 0; i < 8; i++) { int idx = base + i; int x = (idx < M) ? bcnt[idx] : 0; v[i] = x; ts += x; }
    lds[t] = ts; __syncthreads();
#pragma unroll
    for (int d = 1; d < 256; d <<= 1) {
        int x = (t >= d) ? lds[t - d] : 0; __syncthreads();
        lds[t] += x; __syncthreads();
    }
    int run = lds[t] - ts;
#pragma unroll
    for (int i = 0; i < 8; i++) {
        int idx = base + i;
        if (idx < M) { prp[idx] = run; run += v[i]; }
    }
    if (t == 255) prp[M] = lds[255];  // == E
}

// pairs[pos] = src | (dst&63)<<17 (src < 2^17). Each block owns exclusive
// contiguous runs per bucket -> single-writer cachelines.
__global__ __launch_bounds__(1024) void part_scatter(const int* __restrict__ src,
                                                     const int* __restrict__ dst,
                                                     const int* __restrict__ cntmat,
                                                     const int* __restrict__ prp,
                                                     int* __restrict__ pairs,
                                                     int E, int B, int chunk) {
    __shared__ int cur[BMAX];
    for (int i = threadIdx.x; i < B; i += 1024)
        cur[i] = prp[i] + cntmat[i * NBLK + blockIdx.x];
    __syncthreads();
    int s = blockIdx.x * chunk;
    int en = min(s + chunk, E);
    for (int i = s + threadIdx.x; i < en; i += 1024) {
        int d = dst[i];
        int pos = atomicAdd(&cur[d >> 6], 1);
        pairs[pos] = src[i] | ((d & 63) << 17);
    }
}

// one block per bucket: local hist -> rp, dinv, csr.
__global__ __launch_bounds__(256) void csr_build(const int* __restrict__ pairs,
                                                 const int* __restrict__ prp,
                                                 int* __restrict__ rp,
                                                 float* __restrict__ dinv,
                                                 int* __restrict__ csr,
                                                 int N, int B, int E) {
    __shared__ int hist[64], cur[64];
    int b = blockIdx.x;
    int t = threadIdx.x;
    if (t < 64) hist[t] = 0;
    __syncthreads();
    int r0 = prp[b], r1 = prp[b + 1];
    for (int i = r0 + t; i < r1; i += 256)
        atomicAdd(&hist[pairs[i] >> 17], 1);
    __syncthreads();
    if (t == 0) {
        int run = r0;
        for (int k = 0; k < 64; k++) { cur[k] = run; run += hist[k]; }
    }
    __syncthreads();
    if (t < 64) {
        int node = b * 64 + t;
        if (node < N) {
            rp[node] = cur[t];
            dinv[node] = rsqrtf((float)(hist[t] + 1));  // +1 self loop
        }
    }
    if (b == B - 1 && t == 0) rp[N] = E;
    __syncthreads();
    for (int i = r0 + t; i < r1; i += 256) {
        int v = pairs[i];
        int pos = atomicAdd(&cur[v >> 17], 1);
        csr[pos] = v & 0x1FFFF;
    }
}

// G[row][j] = dinv[row] * sum_k X[row][k]*W[k][j]
// lane j owns output column j. W held in VGPRs in chunks of KC (no spill);
// X tile staged in LDS, read back as wave-uniform float4 broadcasts.
template <int K, int RPW, int KC>
__global__ __launch_bounds__(256) void gemm_dinv(const float* __restrict__ X,
                                                 const float* __restrict__ W,
                                                 const float* __restrict__ dinv,
                                                 float* __restrict__ G, int N) {
    constexpr int ROWS = 4 * RPW;
    __shared__ float Xl[ROWS * K];
    int lane = threadIdx.x & 63;
    int wid  = threadIdx.x >> 6;
    int row0 = blockIdx.x * ROWS;
    const float* xsrc = X + (size_t)row0 * K;

    if (row0 + ROWS <= N) {
#pragma unroll
        for (int i = threadIdx.x; i < ROWS * K / 4; i += 256)
            ((float4*)Xl)[i] = ((const float4*)xsrc)[i];
    } else {
        int avail = (N - row0) * K;
        for (int i = threadIdx.x; i < ROWS * K; i += 256)
            Xl[i] = (i < avail) ? xsrc[i] : 0.f;
    }
    __syncthreads();

    float acc[RPW];
#pragma unroll
    for (int r = 0; r < RPW; r++) acc[r] = 0.f;
    int rbase = wid * RPW;

#pragma unroll 1  // chunks sequential: only one w[KC] live at a time (no spill)
    for (int c = 0; c < K / KC; c++) {
        float w[KC];
#pragma unroll
        for (int k = 0; k < KC; k++) w[k] = W[(c * KC + k) * 64 + lane];
#pragma unroll
        for (int r = 0; r < RPW; r++) {
            const float* xrow = &Xl[(rbase + r) * K + c * KC];
#pragma unroll
            for (int k4 = 0; k4 < KC / 4; k4++) {
                float4 xv = *(const float4*)&xrow[k4 * 4];  // wave-uniform broadcast
                acc[r] = fmaf(xv.x, w[k4 * 4 + 0], acc[r]);
                acc[r] = fmaf(xv.y, w[k4 * 4 + 1], acc[r]);
                acc[r] = fmaf(xv.z, w[k4 * 4 + 2], acc[r]);
                acc[r] = fmaf(xv.w, w[k4 * 4 + 3], acc[r]);
            }
        }
    }
#pragma unroll
    for (int r = 0; r < RPW; r++) {
        int row = row0 + rbase + r;
        if (row < N) G[(size_t)row * 64 + lane] = dinv[row] * acc[r];
    }
}

// H[node] = relu(dinv[node] * (G[node] + sum_{src} G[src]) + b)
// wave = 1 node; 4 groups x 16 lanes; 4 edges in flight per group (ILP).
__global__ __launch_bounds__(256) void aggregate(const float* __restrict__ G,
                                                 const int* __restrict__ rp,
                                                 const int* __restrict__ csr,
                                                 const float* __restrict__ dinv,
                                                 const float* __restrict__ bias,
                                                 float* __restrict__ H, int N) {
    int node = blockIdx.x * 4 + (threadIdx.x >> 6);
    if (node >= N) return;
    node = __builtin_amdgcn_readfirstlane(node);
    int lane = threadIdx.x & 63;
    int grp = lane >> 4, sub = lane & 15;
    int beg = rp[node], end = rp[node + 1];
    const float4* G4 = (const float4*)G;

    float4 acc = make_float4(0.f, 0.f, 0.f, 0.f);
    if (grp == 0) acc = G4[(size_t)node * 16 + sub];  // self loop

    int e = beg + grp;
    for (; e + 12 < end; e += 16) {
        int s0 = csr[e], s1 = csr[e + 4], s2 = csr[e + 8], s3 = csr[e + 12];
        float4 v0 = G4[(size_t)s0 * 16 + sub];
        float4 v1 = G4[(size_t)s1 * 16 + sub];
        float4 v2 = G4[(size_t)s2 * 16 + sub];
        float4 v3 = G4[(size_t)s3 * 16 + sub];
        acc.x += v0.x; acc.y += v0.y; acc.z += v0.z; acc.w += v0.w;
        acc.x += v1.x; acc.y += v1.y; acc.z += v1.z; acc.w += v1.w;
        acc.x += v2.x; acc.y += v2.y; acc.z += v2.z; acc.w += v2.w;
        acc.x += v3.x; acc.y += v3.y; acc.z += v3.z; acc.w += v3.w;
    }
    for (; e < end; e += 4) {
        int s0 = csr[e];
        float4 v0 = G4[(size_t)s0 * 16 + sub];
        acc.x += v0.x; acc.y += v0.y; acc.z += v0.z; acc.w += v0.w;
    }
#pragma unroll
    for (int m = 16; m <= 32; m <<= 1) {
        acc.x += __shfl_xor(acc.x, m, 64);
        acc.y += __shfl_xor(acc.y, m, 64);
        acc.z += __shfl_xor(acc.z, m, 64);
        acc.w += __shfl_xor(acc.w, m, 64);
    }
    if (grp == 0) {
        float dn = dinv[node];
        float4 bv = ((const float4*)bias)[sub];
        float4 r;
        r.x = fmaxf(fmaf(dn, acc.x, bv.x), 0.f);
        r.y = fmaxf(fmaf(dn, acc.y, bv.y), 0.f);
        r.z = fmaxf(fmaf(dn, acc.z, bv.z), 0.f);
        r.w = fmaxf(fmaf(dn, acc.w, bv.w), 0.f);
        ((float4*)H)[(size_t)node * 16 + sub] = r;
    }
}

// wave = 1 graph; binary search sorted batch for [start,end), mean over rows.
__global__ __launch_bounds__(256) void pool_kernel(const float* __restrict__ H,
                                                   const int* __restrict__ batch,
                                                   float* __restrict__ pooled,
                                                   int N, int NG) {
    int g = blockIdx.x * 4 + (threadIdx.x >> 6);
    if (g >= NG) return;
    g = __builtin_amdgcn_readfirstlane(g);
    int lane = threadIdx.x & 63;
    int grp = lane >> 4, sub = lane & 15;

    int lo = 0, hi = N;
    while (lo < hi) { int m = (lo + hi) >> 1; if (batch[m] < g) lo = m + 1; else hi = m; }
    int start = lo;
    int lo2 = start, hi2 = N;
    while (lo2 < hi2) { int m = (lo2 + hi2) >> 1; if (batch[m] < g + 1) lo2 = m + 1; else hi2 = m; }
    int end = lo2;

    const float4* H4 = (const float4*)H;
    float4 acc = make_float4(0.f, 0.f, 0.f, 0.f);
    for (int n = start + grp; n < end; n += 4) {
        float4 v = H4[(size_t)n * 16 + sub];
        acc.x += v.x; acc.y += v.y; acc.z += v.z; acc.w += v.w;
    }
#pragma unroll
    for (int m = 16; m <= 32; m <<= 1) {
        acc.x += __shfl_xor(acc.x, m, 64);
        acc.y += __shfl_xor(acc.y, m, 64);
        acc.z += __shfl_xor(acc.z, m, 64);
        acc.w += __shfl_xor(acc.w, m, 64);
    }
    if (grp == 0) {
        float inv = 1.0f / fmaxf((float)(end - start), 1.0f);
        float4 r;
        r.x = acc.x * inv; r.y = acc.y * inv; r.z = acc.z * inv; r.w = acc.w * inv;
        ((float4*)pooled)[(size_t)g * 16 + sub] = r;
    }
}

// per graph: z = relu(pooled@Wc1+bc1); out = z@Wc2+bc2
__global__ __launch_bounds__(64) void classifier(const float* __restrict__ pooled,
                                                 const float* __restrict__ Wc1,
                                                 const float* __restrict__ bc1,
                                                 const float* __restrict__ Wc2,
                                                 const float* __restrict__ bc2,
                                                 float* __restrict__ out) {
    int g = blockIdx.x;
    int t = threadIdx.x;
    __shared__ float p[64];
    __shared__ float z[32];
    p[t] = pooled[(size_t)g * 64 + t];
    __syncthreads();
    if (t < 32) {
        float a = bc1[t];
        for (int f = 0; f < 64; f++) a = fmaf(p[f], Wc1[f * 32 + t], a);
        z[t] = fmaxf(a, 0.f);
    }
    __syncthreads();
    if (t < 10) {
        float a = bc2[t];
        for (int j = 0; j < 32; j++) a = fmaf(z[j], Wc2[j * 10 + t], a);
        out[(size_t)g * 10 + t] = a;
    }
}

extern "C" void kernel_launch(void* const* d_in, const int* in_sizes, int n_in,
                              void* d_out, int out_size, void* d_ws, size_t ws_size,
                              hipStream_t stream) {
    const float* x   = (const float*)d_in[0];
    const int*   ei  = (const int*)d_in[1];
    const int*   bat = (const int*)d_in[2];
    const float* W1  = (const float*)d_in[3];
    const float* b1  = (const float*)d_in[4];
    const float* W2  = (const float*)d_in[5];
    const float* b2  = (const float*)d_in[6];
    const float* W3  = (const float*)d_in[7];
    const float* b3  = (const float*)d_in[8];
    const float* Wc1 = (const float*)d_in[9];
    const float* bc1 = (const float*)d_in[10];
    const float* Wc2 = (const float*)d_in[11];
    const float* bc2 = (const float*)d_in[12];

    const int N  = in_sizes[0] / 128;
    const int E  = in_sizes[1] / 2;
    const int NG = out_size / 10;
    const int B  = (N + 63) >> 6;  // <= BMAX for N <= 131072
    const int* srcp = ei;
    const int* dstp = ei + E;

    char* ws = (char*)d_ws;
    size_t off = 0;
    auto alloc = [&](size_t bytes) -> void* {
        void* p = ws + off;
        off += (bytes + 255) / 256 * 256;
        return p;
    };
    float* G      = (float*)alloc((size_t)N * 64 * 4);
    float* H      = (float*)alloc((size_t)N * 64 * 4);
    int*   pairs  = (int*)H;  // alias: pairs (E ints) dead before first aggregate writes H
    int*   csr    = (int*)alloc((size_t)E * 4);
    int*   rp     = (int*)alloc((size_t)(N + 1) * 4);
    float* dinv   = (float*)alloc((size_t)N * 4);
    int*   bcnt   = (int*)alloc((size_t)BMAX * 4);
    int*   prp    = (int*)alloc((size_t)(BMAX + 1) * 4);
    int*   cntmat = (int*)alloc((size_t)BMAX * NBLK * 4);  // 2 MB
    float* pooled = (float*)alloc((size_t)NG * 64 * 4);
    (void)ws_size; (void)n_in;

    // --- CSR build (two-level multisplit) ---
    const int chunk = (E + NBLK - 1) / NBLK;
    part_hist<<<NBLK, 1024, 0, stream>>>(dstp, cntmat, E, B, chunk);
    part_scan<<<(B + 3) / 4, 256, 0, stream>>>(cntmat, bcnt, B);
    bucket_scan<<<1, 256, 0, stream>>>(bcnt, prp, B);
    part_scatter<<<NBLK, 1024, 0, stream>>>(srcp, dstp, cntmat, prp, pairs, E, B, chunk);
    csr_build<<<B, 256, 0, stream>>>(pairs, prp, rp, dinv, csr, N, B, E);

    // --- 3 GCN layers: 32 rows/block GEMM (W in 64-reg chunks) + pull-aggregate ---
    gemm_dinv<128, 8, 64><<<(N + 31) / 32, 256, 0, stream>>>(x, W1, dinv, G, N);
    aggregate<<<(N + 3) / 4, 256, 0, stream>>>(G, rp, csr, dinv, b1, H, N);
    gemm_dinv<64, 8, 64><<<(N + 31) / 32, 256, 0, stream>>>(H, W2, dinv, G, N);
    aggregate<<<(N + 3) / 4, 256, 0, stream>>>(G, rp, csr, dinv, b2, H, N);
    gemm_dinv<64, 8, 64><<<(N + 31) / 32, 256, 0, stream>>>(H, W3, dinv, G, N);
    aggregate<<<(N + 3) / 4, 256, 0, stream>>>(G, rp, csr, dinv, b3, H, N);

    // --- pool + classifier ---
    pool_kernel<<<(NG + 3) / 4, 256, 0, stream>>>(H, bat, pooled, N, NG);
    classifier<<<NG, 64, 0, stream>>>(pooled, Wc1, bc1, Wc2, bc2, (float*)d_out);
}

// Round 8
// 644.921 us; speedup vs baseline: 3.7618x; 1.2480x over previous
//
#include <hip/hip_runtime.h>
#include <hip/hip_bf16.h>

// GCN forward. CSR build via two-level multisplit (radix-partition style):
//   part_hist -> part_scan -> bucket_scan -> part_scatter (single-writer
//   cachelines per block -> write-combining) -> csr_build.
// Then 3x (GEMM -> pull-aggregate -> ReLU), binary-search mean-pool, MLP.
// norm = dinv[src]*dinv[dst] factored into GEMM / aggregate epilogues.
// GEMM history: w[128] spilled (r3: 3.9GB scratch, 950us); w[64] ALSO spilled
// (r7: VGPR=256, occ 10%, WRITE 205MB vs 25.6 ideal, 116us). KC=16 now.
// Scatter history: naive 195MB/270us; shared-window 163MB/247us (XCD L2
// ping-pong); multisplit single-writer windows fixed it.

#define BMAX 2048  // buckets = ceil(N/64); N <= 131072
#define NBLK 256   // partition blocks (cntmat inner dim)

__global__ __launch_bounds__(1024) void part_hist(const int* __restrict__ dst,
                                                  int* __restrict__ cntmat,
                                                  int E, int B, int chunk) {
    __shared__ int hist[BMAX];
    for (int i = threadIdx.x; i < BMAX; i += 1024) hist[i] = 0;
    __syncthreads();
    int s = blockIdx.x * chunk;
    int en = min(s + chunk, E);
    for (int i = s + threadIdx.x; i < en; i += 1024)
        atomicAdd(&hist[dst[i] >> 6], 1);
    __syncthreads();
    for (int i = threadIdx.x; i < B; i += 1024)
        cntmat[i * NBLK + blockIdx.x] = hist[i];
}

// one wave per bucket: exclusive scan of cntmat[b][0..256) in 4x64 chunks.
__global__ __launch_bounds__(256) void part_scan(int* __restrict__ cntmat,
                                                 int* __restrict__ bcnt, int B) {
    int w = threadIdx.x >> 6;
    int lane = threadIdx.x & 63;
    int b = blockIdx.x * 4 + w;
    if (b >= B) return;
    int carry = 0;
#pragma unroll
    for (int j = 0; j < NBLK / 64; j++) {
        int idx = b * NBLK + j * 64 + lane;
        int v = cntmat[idx];
        int x = v;
#pragma unroll
        for (int d = 1; d < 64; d <<= 1) {
            int t = __shfl_up(x, d, 64);
            if (lane >= d) x += t;
        }
        cntmat[idx] = x - v + carry;          // exclusive within bucket
        carry += __shfl(x, 63, 64);           // add chunk total
    }
    if (lane == 0) bcnt[b] = carry;
}

// single block: exclusive scan of bcnt[0..M) -> prp (bucket starts).
__global__ __launch_bounds__(256) void bucket_scan(const int* __restrict__ bcnt,
                                                   int* __restrict__ prp, int M) {
    __shared__ int lds[256];
    int t = threadIdx.x;
    int base = t * 8;
    int v[8]; int ts = 0;
#pragma unroll
    for (int i = 0; i < 8; i++) { int idx = base + i; int x = (idx < M) ? bcnt[idx] : 0; v[i] = x; ts += x; }
    lds[t] = ts; __syncthreads();
#pragma unroll
    for (int d = 1; d < 256; d <<= 1) {
        int x = (t >= d) ? lds[t - d] : 0; __syncthreads();
        lds[t] += x; __syncthreads();
    }
    int run = lds[t] - ts;
#pragma unroll
    for (int i = 0; i < 8; i++) {
        int idx = base + i;
        if (idx < M) { prp[idx] = run; run += v[i]; }
    }
    if (t == 255) prp[M] = lds[255];  // == E
}

// pairs[pos] = src | (dst&63)<<17 (src < 2^17). Each block owns exclusive
// contiguous runs per bucket -> single-writer cachelines.
__global__ __launch_bounds__(1024) void part_scatter(const int* __restrict__ src,
                                                     const int* __restrict__ dst,
                                                     const int* __restrict__ cntmat,
                                                     const int* __restrict__ prp,
                                                     int* __restrict__ pairs,
                                                     int E, int B, int chunk) {
    __shared__ int cur[BMAX];
    for (int i = threadIdx.x; i < B; i += 1024)
        cur[i] = prp[i] + cntmat[i * NBLK + blockIdx.x];
    __syncthreads();
    int s = blockIdx.x * chunk;
    int en = min(s + chunk, E);
    for (int i = s + threadIdx.x; i < en; i += 1024) {
        int d = dst[i];
        int pos = atomicAdd(&cur[d >> 6], 1);
        pairs[pos] = src[i] | ((d & 63) << 17);
    }
}

// one block per bucket: local hist -> rp, dinv, csr.
__global__ __launch_bounds__(256) void csr_build(const int* __restrict__ pairs,
                                                 const int* __restrict__ prp,
                                                 int* __restrict__ rp,
                                                 float* __restrict__ dinv,
                                                 int* __restrict__ csr,
                                                 int N, int B, int E) {
    __shared__ int hist[64], cur[64];
    int b = blockIdx.x;
    int t = threadIdx.x;
    if (t < 64) hist[t] = 0;
    __syncthreads();
    int r0 = prp[b], r1 = prp[b + 1];
    for (int i = r0 + t; i < r1; i += 256)
        atomicAdd(&hist[pairs[i] >> 17], 1);
    __syncthreads();
    if (t == 0) {
        int run = r0;
        for (int k = 0; k < 64; k++) { cur[k] = run; run += hist[k]; }
    }
    __syncthreads();
    if (t < 64) {
        int node = b * 64 + t;
        if (node < N) {
            rp[node] = cur[t];
            dinv[node] = rsqrtf((float)(hist[t] + 1));  // +1 self loop
        }
    }
    if (b == B - 1 && t == 0) rp[N] = E;
    __syncthreads();
    for (int i = r0 + t; i < r1; i += 256) {
        int v = pairs[i];
        int pos = atomicAdd(&cur[v >> 17], 1);
        csr[pos] = v & 0x1FFFF;
    }
}

// G[row][j] = dinv[row] * sum_k X[row][k]*W[k][j]
// lane j owns output column j. W held in VGPRs in SMALL chunks of KC=16
// (w[16]+acc[8] fits register budget -> no spill, high occupancy);
// X tile staged in LDS, read back as wave-uniform float4 broadcasts.
template <int K, int RPW, int KC>
__global__ __launch_bounds__(256) void gemm_dinv(const float* __restrict__ X,
                                                 const float* __restrict__ W,
                                                 const float* __restrict__ dinv,
                                                 float* __restrict__ G, int N) {
    constexpr int ROWS = 4 * RPW;
    __shared__ float Xl[ROWS * K];
    int lane = threadIdx.x & 63;
    int wid  = threadIdx.x >> 6;
    int row0 = blockIdx.x * ROWS;
    const float* xsrc = X + (size_t)row0 * K;

    if (row0 + ROWS <= N) {
#pragma unroll
        for (int i = threadIdx.x; i < ROWS * K / 4; i += 256)
            ((float4*)Xl)[i] = ((const float4*)xsrc)[i];
    } else {
        int avail = (N - row0) * K;
        for (int i = threadIdx.x; i < ROWS * K; i += 256)
            Xl[i] = (i < avail) ? xsrc[i] : 0.f;
    }
    __syncthreads();

    float acc[RPW];
#pragma unroll
    for (int r = 0; r < RPW; r++) acc[r] = 0.f;
    int rbase = wid * RPW;

#pragma unroll 1  // chunks sequential: only one w[KC] live at a time
    for (int c = 0; c < K / KC; c++) {
        float w[KC];
#pragma unroll
        for (int k = 0; k < KC; k++) w[k] = W[(c * KC + k) * 64 + lane];
#pragma unroll
        for (int r = 0; r < RPW; r++) {
            const float* xrow = &Xl[(rbase + r) * K + c * KC];
#pragma unroll
            for (int k4 = 0; k4 < KC / 4; k4++) {
                float4 xv = *(const float4*)&xrow[k4 * 4];  // wave-uniform broadcast
                acc[r] = fmaf(xv.x, w[k4 * 4 + 0], acc[r]);
                acc[r] = fmaf(xv.y, w[k4 * 4 + 1], acc[r]);
                acc[r] = fmaf(xv.z, w[k4 * 4 + 2], acc[r]);
                acc[r] = fmaf(xv.w, w[k4 * 4 + 3], acc[r]);
            }
        }
    }
#pragma unroll
    for (int r = 0; r < RPW; r++) {
        int row = row0 + rbase + r;
        if (row < N) G[(size_t)row * 64 + lane] = dinv[row] * acc[r];
    }
}

// H[node] = relu(dinv[node] * (G[node] + sum_{src} G[src]) + b)
// wave = 1 node; 4 groups x 16 lanes; 8 edges in flight per group (ILP;
// avg degree 32 -> one 8-deep batch covers a typical node's group share).
__global__ __launch_bounds__(256) void aggregate(const float* __restrict__ G,
                                                 const int* __restrict__ rp,
                                                 const int* __restrict__ csr,
                                                 const float* __restrict__ dinv,
                                                 const float* __restrict__ bias,
                                                 float* __restrict__ H, int N) {
    int node = blockIdx.x * 4 + (threadIdx.x >> 6);
    if (node >= N) return;
    node = __builtin_amdgcn_readfirstlane(node);
    int lane = threadIdx.x & 63;
    int grp = lane >> 4, sub = lane & 15;
    int beg = rp[node], end = rp[node + 1];
    const float4* G4 = (const float4*)G;

    float4 acc = make_float4(0.f, 0.f, 0.f, 0.f);
    if (grp == 0) acc = G4[(size_t)node * 16 + sub];  // self loop

    int e = beg + grp;
    for (; e + 28 < end; e += 32) {
        int s[8];
        float4 v[8];
#pragma unroll
        for (int j = 0; j < 8; j++) s[j] = csr[e + j * 4];
#pragma unroll
        for (int j = 0; j < 8; j++) v[j] = G4[(size_t)s[j] * 16 + sub];
#pragma unroll
        for (int j = 0; j < 8; j++) {
            acc.x += v[j].x; acc.y += v[j].y; acc.z += v[j].z; acc.w += v[j].w;
        }
    }
    for (; e < end; e += 4) {
        int s0 = csr[e];
        float4 v0 = G4[(size_t)s0 * 16 + sub];
        acc.x += v0.x; acc.y += v0.y; acc.z += v0.z; acc.w += v0.w;
    }
#pragma unroll
    for (int m = 16; m <= 32; m <<= 1) {
        acc.x += __shfl_xor(acc.x, m, 64);
        acc.y += __shfl_xor(acc.y, m, 64);
        acc.z += __shfl_xor(acc.z, m, 64);
        acc.w += __shfl_xor(acc.w, m, 64);
    }
    if (grp == 0) {
        float dn = dinv[node];
        float4 bv = ((const float4*)bias)[sub];
        float4 r;
        r.x = fmaxf(fmaf(dn, acc.x, bv.x), 0.f);
        r.y = fmaxf(fmaf(dn, acc.y, bv.y), 0.f);
        r.z = fmaxf(fmaf(dn, acc.z, bv.z), 0.f);
        r.w = fmaxf(fmaf(dn, acc.w, bv.w), 0.f);
        ((float4*)H)[(size_t)node * 16 + sub] = r;
    }
}

// wave = 1 graph; binary search sorted batch for [start,end), mean over rows.
__global__ __launch_bounds__(256) void pool_kernel(const float* __restrict__ H,
                                                   const int* __restrict__ batch,
                                                   float* __restrict__ pooled,
                                                   int N, int NG) {
    int g = blockIdx.x * 4 + (threadIdx.x >> 6);
    if (g >= NG) return;
    g = __builtin_amdgcn_readfirstlane(g);
    int lane = threadIdx.x & 63;
    int grp = lane >> 4, sub = lane & 15;

    int lo = 0, hi = N;
    while (lo < hi) { int m = (lo + hi) >> 1; if (batch[m] < g) lo = m + 1; else hi = m; }
    int start = lo;
    int lo2 = start, hi2 = N;
    while (lo2 < hi2) { int m = (lo2 + hi2) >> 1; if (batch[m] < g + 1) lo2 = m + 1; else hi2 = m; }
    int end = lo2;

    const float4* H4 = (const float4*)H;
    float4 acc = make_float4(0.f, 0.f, 0.f, 0.f);
    for (int n = start + grp; n < end; n += 4) {
        float4 v = H4[(size_t)n * 16 + sub];
        acc.x += v.x; acc.y += v.y; acc.z += v.z; acc.w += v.w;
    }
#pragma unroll
    for (int m = 16; m <= 32; m <<= 1) {
        acc.x += __shfl_xor(acc.x, m, 64);
        acc.y += __shfl_xor(acc.y, m, 64);
        acc.z += __shfl_xor(acc.z, m, 64);
        acc.w += __shfl_xor(acc.w, m, 64);
    }
    if (grp == 0) {
        float inv = 1.0f / fmaxf((float)(end - start), 1.0f);
        float4 r;
        r.x = acc.x * inv; r.y = acc.y * inv; r.z = acc.z * inv; r.w = acc.w * inv;
        ((float4*)pooled)[(size_t)g * 16 + sub] = r;
    }
}

// per graph: z = relu(pooled@Wc1+bc1); out = z@Wc2+bc2
__global__ __launch_bounds__(64) void classifier(const float* __restrict__ pooled,
                                                 const float* __restrict__ Wc1,
                                                 const float* __restrict__ bc1,
                                                 const float* __restrict__ Wc2,
                                                 const float* __restrict__ bc2,
                                                 float* __restrict__ out) {
    int g = blockIdx.x;
    int t = threadIdx.x;
    __shared__ float p[64];
    __shared__ float z[32];
    p[t] = pooled[(size_t)g * 64 + t];
    __syncthreads();
    if (t < 32) {
        float a = bc1[t];
        for (int f = 0; f < 64; f++) a = fmaf(p[f], Wc1[f * 32 + t], a);
        z[t] = fmaxf(a, 0.f);
    }
    __syncthreads();
    if (t < 10) {
        float a = bc2[t];
        for (int j = 0; j < 32; j++) a = fmaf(z[j], Wc2[j * 10 + t], a);
        out[(size_t)g * 10 + t] = a;
    }
}

extern "C" void kernel_launch(void* const* d_in, const int* in_sizes, int n_in,
                              void* d_out, int out_size, void* d_ws, size_t ws_size,
                              hipStream_t stream) {
    const float* x   = (const float*)d_in[0];
    const int*   ei  = (const int*)d_in[1];
    const int*   bat = (const int*)d_in[2];
    const float* W1  = (const float*)d_in[3];
    const float* b1  = (const float*)d_in[4];
    const float* W2  = (const float*)d_in[5];
    const float* b2  = (const float*)d_in[6];
    const float* W3  = (const float*)d_in[7];
    const float* b3  = (const float*)d_in[8];
    const float* Wc1 = (const float*)d_in[9];
    const float* bc1 = (const float*)d_in[10];
    const float* Wc2 = (const float*)d_in[11];
    const float* bc2 = (const float*)d_in[12];

    const int N  = in_sizes[0] / 128;
    const int E  = in_sizes[1] / 2;
    const int NG = out_size / 10;
    const int B  = (N + 63) >> 6;  // <= BMAX for N <= 131072
    const int* srcp = ei;
    const int* dstp = ei + E;

    char* ws = (char*)d_ws;
    size_t off = 0;
    auto alloc = [&](size_t bytes) -> void* {
        void* p = ws + off;
        off += (bytes + 255) / 256 * 256;
        return p;
    };
    float* G      = (float*)alloc((size_t)N * 64 * 4);
    float* H      = (float*)alloc((size_t)N * 64 * 4);
    int*   pairs  = (int*)H;  // alias: pairs (E ints) dead before first aggregate writes H
    int*   csr    = (int*)alloc((size_t)E * 4);
    int*   rp     = (int*)alloc((size_t)(N + 1) * 4);
    float* dinv   = (float*)alloc((size_t)N * 4);
    int*   bcnt   = (int*)alloc((size_t)BMAX * 4);
    int*   prp    = (int*)alloc((size_t)(BMAX + 1) * 4);
    int*   cntmat = (int*)alloc((size_t)BMAX * NBLK * 4);  // 2 MB
    float* pooled = (float*)alloc((size_t)NG * 64 * 4);
    (void)ws_size; (void)n_in;

    // --- CSR build (two-level multisplit) ---
    const int chunk = (E + NBLK - 1) / NBLK;
    part_hist<<<NBLK, 1024, 0, stream>>>(dstp, cntmat, E, B, chunk);
    part_scan<<<(B + 3) / 4, 256, 0, stream>>>(cntmat, bcnt, B);
    bucket_scan<<<1, 256, 0, stream>>>(bcnt, prp, B);
    part_scatter<<<NBLK, 1024, 0, stream>>>(srcp, dstp, cntmat, prp, pairs, E, B, chunk);
    csr_build<<<B, 256, 0, stream>>>(pairs, prp, rp, dinv, csr, N, B, E);

    // --- 3 GCN layers: 32 rows/block GEMM (W in 16-reg chunks) + pull-aggregate ---
    gemm_dinv<128, 8, 16><<<(N + 31) / 32, 256, 0, stream>>>(x, W1, dinv, G, N);
    aggregate<<<(N + 3) / 4, 256, 0, stream>>>(G, rp, csr, dinv, b1, H, N);
    gemm_dinv<64, 8, 16><<<(N + 31) / 32, 256, 0, stream>>>(H, W2, dinv, G, N);
    aggregate<<<(N + 3) / 4, 256, 0, stream>>>(G, rp, csr, dinv, b2, H, N);
    gemm_dinv<64, 8, 16><<<(N + 31) / 32, 256, 0, stream>>>(H, W3, dinv, G, N);
    aggregate<<<(N + 3) / 4, 256, 0, stream>>>(G, rp, csr, dinv, b3, H, N);

    // --- pool + classifier ---
    pool_kernel<<<(NG + 3) / 4, 256, 0, stream>>>(H, bat, pooled, N, NG);
    classifier<<<NG, 64, 0, stream>>>(pooled, Wc1, bc1, Wc2, bc2, (float*)d_out);
}

// Round 9
// 600.982 us; speedup vs baseline: 4.0368x; 1.0731x over previous
//
#include <hip/hip_runtime.h>
#include <hip/hip_bf16.h>

// GCN forward. CSR build via two-level multisplit (radix-partition style):
//   part_hist -> part_scan -> bucket_scan -> part_scatter (single-writer
//   cachelines per block -> write-combining) -> csr_build.
// Then 3x (GEMM -> pull-aggregate -> ReLU), fused mean-pool+MLP classifier.
// norm = dinv[src]*dinv[dst] factored into GEMM / aggregate epilogues.
// G (gather table) stored BF16: gather rows 128B instead of 256B; accumulate
// f32, H stays f32. r8 counters: aggregate FETCH=363MB at 3.7TB/s BW-bound,
// src random -> no locality fix possible, so halve bytes/row.
// GEMM history: w[128]/w[64] spilled (r3/r7); KC=16 fits (no spill).
// Scatter history: naive 195MB/270us; shared-window 163MB/247us (XCD L2
// ping-pong); multisplit single-writer windows fixed it.

typedef unsigned short u16;

__device__ __forceinline__ float bf2f(u16 u) {
    return __uint_as_float(((unsigned int)u) << 16);
}
__device__ __forceinline__ u16 f2bf(float f) {
    unsigned int x = __float_as_uint(f);
    return (u16)((x + 0x7fffu + ((x >> 16) & 1u)) >> 16);  // RNE
}

#define BMAX 2048  // buckets = ceil(N/64); N <= 131072
#define NBLK 256   // partition blocks (cntmat inner dim)

__global__ __launch_bounds__(1024) void part_hist(const int* __restrict__ dst,
                                                  int* __restrict__ cntmat,
                                                  int E, int B, int chunk) {
    __shared__ int hist[BMAX];
    for (int i = threadIdx.x; i < BMAX; i += 1024) hist[i] = 0;
    __syncthreads();
    int s = blockIdx.x * chunk;
    int en = min(s + chunk, E);
    for (int i = s + threadIdx.x; i < en; i += 1024)
        atomicAdd(&hist[dst[i] >> 6], 1);
    __syncthreads();
    for (int i = threadIdx.x; i < B; i += 1024)
        cntmat[i * NBLK + blockIdx.x] = hist[i];
}

// one wave per bucket: exclusive scan of cntmat[b][0..256) in 4x64 chunks.
__global__ __launch_bounds__(256) void part_scan(int* __restrict__ cntmat,
                                                 int* __restrict__ bcnt, int B) {
    int w = threadIdx.x >> 6;
    int lane = threadIdx.x & 63;
    int b = blockIdx.x * 4 + w;
    if (b >= B) return;
    int carry = 0;
#pragma unroll
    for (int j = 0; j < NBLK / 64; j++) {
        int idx = b * NBLK + j * 64 + lane;
        int v = cntmat[idx];
        int x = v;
#pragma unroll
        for (int d = 1; d < 64; d <<= 1) {
            int t = __shfl_up(x, d, 64);
            if (lane >= d) x += t;
        }
        cntmat[idx] = x - v + carry;          // exclusive within bucket
        carry += __shfl(x, 63, 64);           // add chunk total
    }
    if (lane == 0) bcnt[b] = carry;
}

// single block: exclusive scan of bcnt[0..M) -> prp (bucket starts).
__global__ __launch_bounds__(256) void bucket_scan(const int* __restrict__ bcnt,
                                                   int* __restrict__ prp, int M) {
    __shared__ int lds[256];
    int t = threadIdx.x;
    int base = t * 8;
    int v[8]; int ts = 0;
#pragma unroll
    for (int i = 0; i < 8; i++) { int idx = base + i; int x = (idx < M) ? bcnt[idx] : 0; v[i] = x; ts += x; }
    lds[t] = ts; __syncthreads();
#pragma unroll
    for (int d = 1; d < 256; d <<= 1) {
        int x = (t >= d) ? lds[t - d] : 0; __syncthreads();
        lds[t] += x; __syncthreads();
    }
    int run = lds[t] - ts;
#pragma unroll
    for (int i = 0; i < 8; i++) {
        int idx = base + i;
        if (idx < M) { prp[idx] = run; run += v[i]; }
    }
    if (t == 255) prp[M] = lds[255];  // == E
}

// pairs[pos] = src | (dst&63)<<17 (src < 2^17). Each block owns exclusive
// contiguous runs per bucket -> single-writer cachelines.
__global__ __launch_bounds__(1024) void part_scatter(const int* __restrict__ src,
                                                     const int* __restrict__ dst,
                                                     const int* __restrict__ cntmat,
                                                     const int* __restrict__ prp,
                                                     int* __restrict__ pairs,
                                                     int E, int B, int chunk) {
    __shared__ int cur[BMAX];
    for (int i = threadIdx.x; i < B; i += 1024)
        cur[i] = prp[i] + cntmat[i * NBLK + blockIdx.x];
    __syncthreads();
    int s = blockIdx.x * chunk;
    int en = min(s + chunk, E);
    for (int i = s + threadIdx.x; i < en; i += 1024) {
        int d = dst[i];
        int pos = atomicAdd(&cur[d >> 6], 1);
        pairs[pos] = src[i] | ((d & 63) << 17);
    }
}

// one block per bucket: local hist -> rp, dinv, csr.
__global__ __launch_bounds__(256) void csr_build(const int* __restrict__ pairs,
                                                 const int* __restrict__ prp,
                                                 int* __restrict__ rp,
                                                 float* __restrict__ dinv,
                                                 int* __restrict__ csr,
                                                 int N, int B, int E) {
    __shared__ int hist[64], cur[64];
    int b = blockIdx.x;
    int t = threadIdx.x;
    if (t < 64) hist[t] = 0;
    __syncthreads();
    int r0 = prp[b], r1 = prp[b + 1];
    for (int i = r0 + t; i < r1; i += 256)
        atomicAdd(&hist[pairs[i] >> 17], 1);
    __syncthreads();
    if (t == 0) {
        int run = r0;
        for (int k = 0; k < 64; k++) { cur[k] = run; run += hist[k]; }
    }
    __syncthreads();
    if (t < 64) {
        int node = b * 64 + t;
        if (node < N) {
            rp[node] = cur[t];
            dinv[node] = rsqrtf((float)(hist[t] + 1));  // +1 self loop
        }
    }
    if (b == B - 1 && t == 0) rp[N] = E;
    __syncthreads();
    for (int i = r0 + t; i < r1; i += 256) {
        int v = pairs[i];
        int pos = atomicAdd(&cur[v >> 17], 1);
        csr[pos] = v & 0x1FFFF;
    }
}

// G[row][j] = bf16( dinv[row] * sum_k X[row][k]*W[k][j] )
// lane j owns output column j. W held in VGPRs in chunks of KC=16 (no spill);
// X tile staged in LDS, read back as wave-uniform float4 broadcasts.
template <int K, int RPW, int KC>
__global__ __launch_bounds__(256) void gemm_dinv(const float* __restrict__ X,
                                                 const float* __restrict__ W,
                                                 const float* __restrict__ dinv,
                                                 u16* __restrict__ G, int N) {
    constexpr int ROWS = 4 * RPW;
    __shared__ float Xl[ROWS * K];
    int lane = threadIdx.x & 63;
    int wid  = threadIdx.x >> 6;
    int row0 = blockIdx.x * ROWS;
    const float* xsrc = X + (size_t)row0 * K;

    if (row0 + ROWS <= N) {
#pragma unroll
        for (int i = threadIdx.x; i < ROWS * K / 4; i += 256)
            ((float4*)Xl)[i] = ((const float4*)xsrc)[i];
    } else {
        int avail = (N - row0) * K;
        for (int i = threadIdx.x; i < ROWS * K; i += 256)
            Xl[i] = (i < avail) ? xsrc[i] : 0.f;
    }
    __syncthreads();

    float acc[RPW];
#pragma unroll
    for (int r = 0; r < RPW; r++) acc[r] = 0.f;
    int rbase = wid * RPW;

#pragma unroll 1  // chunks sequential: only one w[KC] live at a time
    for (int c = 0; c < K / KC; c++) {
        float w[KC];
#pragma unroll
        for (int k = 0; k < KC; k++) w[k] = W[(c * KC + k) * 64 + lane];
#pragma unroll
        for (int r = 0; r < RPW; r++) {
            const float* xrow = &Xl[(rbase + r) * K + c * KC];
#pragma unroll
            for (int k4 = 0; k4 < KC / 4; k4++) {
                float4 xv = *(const float4*)&xrow[k4 * 4];  // wave-uniform broadcast
                acc[r] = fmaf(xv.x, w[k4 * 4 + 0], acc[r]);
                acc[r] = fmaf(xv.y, w[k4 * 4 + 1], acc[r]);
                acc[r] = fmaf(xv.z, w[k4 * 4 + 2], acc[r]);
                acc[r] = fmaf(xv.w, w[k4 * 4 + 3], acc[r]);
            }
        }
    }
#pragma unroll
    for (int r = 0; r < RPW; r++) {
        int row = row0 + rbase + r;
        if (row < N) G[(size_t)row * 64 + lane] = f2bf(dinv[row] * acc[r]);
    }
}

// H[node] = relu(dinv[node] * (G[node] + sum_{src} G[src]) + b), G is bf16.
// wave = 1 node; 4 groups x 16 lanes (lane sub = cols 4sub..4sub+3, ushort4);
// 8 edges in flight per group (avg degree 32 = one full batch).
__global__ __launch_bounds__(256) void aggregate(const u16* __restrict__ G,
                                                 const int* __restrict__ rp,
                                                 const int* __restrict__ csr,
                                                 const float* __restrict__ dinv,
                                                 const float* __restrict__ bias,
                                                 float* __restrict__ H, int N) {
    int node = blockIdx.x * 4 + (threadIdx.x >> 6);
    if (node >= N) return;
    node = __builtin_amdgcn_readfirstlane(node);
    int lane = threadIdx.x & 63;
    int grp = lane >> 4, sub = lane & 15;
    int beg = rp[node], end = rp[node + 1];
    const ushort4* G4 = (const ushort4*)G;

    float4 acc = make_float4(0.f, 0.f, 0.f, 0.f);
    if (grp == 0) {  // self loop
        ushort4 v = G4[(size_t)node * 16 + sub];
        acc.x = bf2f(v.x); acc.y = bf2f(v.y); acc.z = bf2f(v.z); acc.w = bf2f(v.w);
    }

    int e = beg + grp;
    for (; e + 28 < end; e += 32) {
        int s[8];
        ushort4 v[8];
#pragma unroll
        for (int j = 0; j < 8; j++) s[j] = csr[e + j * 4];
#pragma unroll
        for (int j = 0; j < 8; j++) v[j] = G4[(size_t)s[j] * 16 + sub];
#pragma unroll
        for (int j = 0; j < 8; j++) {
            acc.x += bf2f(v[j].x); acc.y += bf2f(v[j].y);
            acc.z += bf2f(v[j].z); acc.w += bf2f(v[j].w);
        }
    }
    for (; e < end; e += 4) {
        ushort4 v = G4[(size_t)csr[e] * 16 + sub];
        acc.x += bf2f(v.x); acc.y += bf2f(v.y); acc.z += bf2f(v.z); acc.w += bf2f(v.w);
    }
#pragma unroll
    for (int m = 16; m <= 32; m <<= 1) {
        acc.x += __shfl_xor(acc.x, m, 64);
        acc.y += __shfl_xor(acc.y, m, 64);
        acc.z += __shfl_xor(acc.z, m, 64);
        acc.w += __shfl_xor(acc.w, m, 64);
    }
    if (grp == 0) {
        float dn = dinv[node];
        float4 bv = ((const float4*)bias)[sub];
        float4 r;
        r.x = fmaxf(fmaf(dn, acc.x, bv.x), 0.f);
        r.y = fmaxf(fmaf(dn, acc.y, bv.y), 0.f);
        r.z = fmaxf(fmaf(dn, acc.z, bv.z), 0.f);
        r.w = fmaxf(fmaf(dn, acc.w, bv.w), 0.f);
        ((float4*)H)[(size_t)node * 16 + sub] = r;
    }
}

// fused: block = 1 graph (64 threads). binary-search [start,end) in sorted
// batch, mean-pool H rows, then z=relu(p@Wc1+bc1), out=z@Wc2+bc2.
__global__ __launch_bounds__(64) void pool_classify(const float* __restrict__ H,
                                                    const int* __restrict__ batch,
                                                    const float* __restrict__ Wc1,
                                                    const float* __restrict__ bc1,
                                                    const float* __restrict__ Wc2,
                                                    const float* __restrict__ bc2,
                                                    float* __restrict__ out,
                                                    int N) {
    int g = blockIdx.x;
    int t = threadIdx.x;
    __shared__ float p[64];
    __shared__ float z[32];

    int lo = 0, hi = N;
    while (lo < hi) { int m = (lo + hi) >> 1; if (batch[m] < g) lo = m + 1; else hi = m; }
    int start = lo;
    int lo2 = start, hi2 = N;
    while (lo2 < hi2) { int m = (lo2 + hi2) >> 1; if (batch[m] < g + 1) lo2 = m + 1; else hi2 = m; }
    int end = lo2;

    float acc = 0.f;
    for (int n = start; n < end; n++) acc += H[(size_t)n * 64 + t];
    p[t] = acc / fmaxf((float)(end - start), 1.0f);
    __syncthreads();
    if (t < 32) {
        float a = bc1[t];
        for (int f = 0; f < 64; f++) a = fmaf(p[f], Wc1[f * 32 + t], a);
        z[t] = fmaxf(a, 0.f);
    }
    __syncthreads();
    if (t < 10) {
        float a = bc2[t];
        for (int j = 0; j < 32; j++) a = fmaf(z[j], Wc2[j * 10 + t], a);
        out[(size_t)g * 10 + t] = a;
    }
}

extern "C" void kernel_launch(void* const* d_in, const int* in_sizes, int n_in,
                              void* d_out, int out_size, void* d_ws, size_t ws_size,
                              hipStream_t stream) {
    const float* x   = (const float*)d_in[0];
    const int*   ei  = (const int*)d_in[1];
    const int*   bat = (const int*)d_in[2];
    const float* W1  = (const float*)d_in[3];
    const float* b1  = (const float*)d_in[4];
    const float* W2  = (const float*)d_in[5];
    const float* b2  = (const float*)d_in[6];
    const float* W3  = (const float*)d_in[7];
    const float* b3  = (const float*)d_in[8];
    const float* Wc1 = (const float*)d_in[9];
    const float* bc1 = (const float*)d_in[10];
    const float* Wc2 = (const float*)d_in[11];
    const float* bc2 = (const float*)d_in[12];

    const int N  = in_sizes[0] / 128;
    const int E  = in_sizes[1] / 2;
    const int NG = out_size / 10;
    const int B  = (N + 63) >> 6;  // <= BMAX for N <= 131072
    const int* srcp = ei;
    const int* dstp = ei + E;

    char* ws = (char*)d_ws;
    size_t off = 0;
    auto alloc = [&](size_t bytes) -> void* {
        void* p = ws + off;
        off += (bytes + 255) / 256 * 256;
        return p;
    };
    u16*   G      = (u16*)alloc((size_t)N * 64 * 2);   // bf16 gather table
    float* H      = (float*)alloc((size_t)N * 64 * 4);
    int*   pairs  = (int*)H;  // alias: pairs (E ints) dead before first aggregate writes H
    int*   csr    = (int*)alloc((size_t)E * 4);
    int*   rp     = (int*)alloc((size_t)(N + 1) * 4);
    float* dinv   = (float*)alloc((size_t)N * 4);
    int*   bcnt   = (int*)alloc((size_t)BMAX * 4);
    int*   prp    = (int*)alloc((size_t)(BMAX + 1) * 4);
    int*   cntmat = (int*)alloc((size_t)BMAX * NBLK * 4);  // 2 MB
    (void)ws_size; (void)n_in;

    // --- CSR build (two-level multisplit) ---
    const int chunk = (E + NBLK - 1) / NBLK;
    part_hist<<<NBLK, 1024, 0, stream>>>(dstp, cntmat, E, B, chunk);
    part_scan<<<(B + 3) / 4, 256, 0, stream>>>(cntmat, bcnt, B);
    bucket_scan<<<1, 256, 0, stream>>>(bcnt, prp, B);
    part_scatter<<<NBLK, 1024, 0, stream>>>(srcp, dstp, cntmat, prp, pairs, E, B, chunk);
    csr_build<<<B, 256, 0, stream>>>(pairs, prp, rp, dinv, csr, N, B, E);

    // --- 3 GCN layers: GEMM (bf16 G out) + pull-aggregate ---
    gemm_dinv<128, 8, 16><<<(N + 31) / 32, 256, 0, stream>>>(x, W1, dinv, G, N);
    aggregate<<<(N + 3) / 4, 256, 0, stream>>>(G, rp, csr, dinv, b1, H, N);
    gemm_dinv<64, 8, 16><<<(N + 31) / 32, 256, 0, stream>>>(H, W2, dinv, G, N);
    aggregate<<<(N + 3) / 4, 256, 0, stream>>>(G, rp, csr, dinv, b2, H, N);
    gemm_dinv<64, 8, 16><<<(N + 31) / 32, 256, 0, stream>>>(H, W3, dinv, G, N);
    aggregate<<<(N + 3) / 4, 256, 0, stream>>>(G, rp, csr, dinv, b3, H, N);

    // --- fused mean-pool + classifier ---
    pool_classify<<<NG, 64, 0, stream>>>(H, bat, Wc1, bc1, Wc2, bc2, (float*)d_out, N);
}

// Round 10
// 492.229 us; speedup vs baseline: 4.9287x; 1.2209x over previous
//
#include <hip/hip_runtime.h>
#include <hip/hip_bf16.h>

// GCN forward. CSR build via two-level multisplit (radix-partition style):
//   part_hist -> part_scan -> bucket_scan -> part_scatter (single-writer
//   cachelines per block -> write-combining) -> csr_build.
// Then 3x (GEMM -> pull-aggregate -> ReLU), fused mean-pool+MLP classifier.
// norm = dinv[src]*dinv[dst] factored into GEMM / aggregate epilogues.
// G (gather table) BF16 (12.8MB, L3-resident): halved gather bytes (r9:
// aggregate 107->78us, FETCH 363->161MB). r9 counters show aggregate now
// latency-bound (2.4TB/s, VALU 36%): widen to 16B/lane row loads (8 lanes/row)
// and 32 rows in flight per wave.
// GEMM history: w[128]/w[64] spilled (r3/r7); KC=16 fits (no spill).
// Scatter history: naive 195MB/270us; shared-window 163MB/247us (XCD L2
// ping-pong); multisplit single-writer windows fixed it.

typedef unsigned short u16;

__device__ __forceinline__ float bf2f(u16 u) {
    return __uint_as_float(((unsigned int)u) << 16);
}
__device__ __forceinline__ u16 f2bf(float f) {
    unsigned int x = __float_as_uint(f);
    return (u16)((x + 0x7fffu + ((x >> 16) & 1u)) >> 16);  // RNE
}
// add a dword-pair of bf16 (lo=bits<<16, hi=bits&0xffff0000) into lo/hi accs
__device__ __forceinline__ void addrow(const uint4 v, float4& lo, float4& hi) {
    lo.x += __uint_as_float(v.x << 16); hi.x += __uint_as_float(v.x & 0xffff0000u);
    lo.y += __uint_as_float(v.y << 16); hi.y += __uint_as_float(v.y & 0xffff0000u);
    lo.z += __uint_as_float(v.z << 16); hi.z += __uint_as_float(v.z & 0xffff0000u);
    lo.w += __uint_as_float(v.w << 16); hi.w += __uint_as_float(v.w & 0xffff0000u);
}

#define BMAX 2048  // buckets = ceil(N/64); N <= 131072
#define NBLK 256   // partition blocks (cntmat inner dim)

__global__ __launch_bounds__(1024) void part_hist(const int* __restrict__ dst,
                                                  int* __restrict__ cntmat,
                                                  int E, int B, int chunk) {
    __shared__ int hist[BMAX];
    for (int i = threadIdx.x; i < BMAX; i += 1024) hist[i] = 0;
    __syncthreads();
    int s = blockIdx.x * chunk;
    int en = min(s + chunk, E);
    for (int i = s + threadIdx.x; i < en; i += 1024)
        atomicAdd(&hist[dst[i] >> 6], 1);
    __syncthreads();
    for (int i = threadIdx.x; i < B; i += 1024)
        cntmat[i * NBLK + blockIdx.x] = hist[i];
}

// one wave per bucket: exclusive scan of cntmat[b][0..256) in 4x64 chunks.
__global__ __launch_bounds__(256) void part_scan(int* __restrict__ cntmat,
                                                 int* __restrict__ bcnt, int B) {
    int w = threadIdx.x >> 6;
    int lane = threadIdx.x & 63;
    int b = blockIdx.x * 4 + w;
    if (b >= B) return;
    int carry = 0;
#pragma unroll
    for (int j = 0; j < NBLK / 64; j++) {
        int idx = b * NBLK + j * 64 + lane;
        int v = cntmat[idx];
        int x = v;
#pragma unroll
        for (int d = 1; d < 64; d <<= 1) {
            int t = __shfl_up(x, d, 64);
            if (lane >= d) x += t;
        }
        cntmat[idx] = x - v + carry;          // exclusive within bucket
        carry += __shfl(x, 63, 64);           // add chunk total
    }
    if (lane == 0) bcnt[b] = carry;
}

// single block: exclusive scan of bcnt[0..M) -> prp (bucket starts).
__global__ __launch_bounds__(256) void bucket_scan(const int* __restrict__ bcnt,
                                                   int* __restrict__ prp, int M) {
    __shared__ int lds[256];
    int t = threadIdx.x;
    int base = t * 8;
    int v[8]; int ts = 0;
#pragma unroll
    for (int i = 0; i < 8; i++) { int idx = base + i; int x = (idx < M) ? bcnt[idx] : 0; v[i] = x; ts += x; }
    lds[t] = ts; __syncthreads();
#pragma unroll
    for (int d = 1; d < 256; d <<= 1) {
        int x = (t >= d) ? lds[t - d] : 0; __syncthreads();
        lds[t] += x; __syncthreads();
    }
    int run = lds[t] - ts;
#pragma unroll
    for (int i = 0; i < 8; i++) {
        int idx = base + i;
        if (idx < M) { prp[idx] = run; run += v[i]; }
    }
    if (t == 255) prp[M] = lds[255];  // == E
}

// pairs[pos] = src | (dst&63)<<17 (src < 2^17). Each block owns exclusive
// contiguous runs per bucket -> single-writer cachelines.
__global__ __launch_bounds__(1024) void part_scatter(const int* __restrict__ src,
                                                     const int* __restrict__ dst,
                                                     const int* __restrict__ cntmat,
                                                     const int* __restrict__ prp,
                                                     int* __restrict__ pairs,
                                                     int E, int B, int chunk) {
    __shared__ int cur[BMAX];
    for (int i = threadIdx.x; i < B; i += 1024)
        cur[i] = prp[i] + cntmat[i * NBLK + blockIdx.x];
    __syncthreads();
    int s = blockIdx.x * chunk;
    int en = min(s + chunk, E);
    for (int i = s + threadIdx.x; i < en; i += 1024) {
        int d = dst[i];
        int pos = atomicAdd(&cur[d >> 6], 1);
        pairs[pos] = src[i] | ((d & 63) << 17);
    }
}

// one block per bucket: local hist -> rp, dinv, csr.
__global__ __launch_bounds__(256) void csr_build(const int* __restrict__ pairs,
                                                 const int* __restrict__ prp,
                                                 int* __restrict__ rp,
                                                 float* __restrict__ dinv,
                                                 int* __restrict__ csr,
                                                 int N, int B, int E) {
    __shared__ int hist[64], cur[64];
    int b = blockIdx.x;
    int t = threadIdx.x;
    if (t < 64) hist[t] = 0;
    __syncthreads();
    int r0 = prp[b], r1 = prp[b + 1];
    for (int i = r0 + t; i < r1; i += 256)
        atomicAdd(&hist[pairs[i] >> 17], 1);
    __syncthreads();
    if (t == 0) {
        int run = r0;
        for (int k = 0; k < 64; k++) { cur[k] = run; run += hist[k]; }
    }
    __syncthreads();
    if (t < 64) {
        int node = b * 64 + t;
        if (node < N) {
            rp[node] = cur[t];
            dinv[node] = rsqrtf((float)(hist[t] + 1));  // +1 self loop
        }
    }
    if (b == B - 1 && t == 0) rp[N] = E;
    __syncthreads();
    for (int i = r0 + t; i < r1; i += 256) {
        int v = pairs[i];
        int pos = atomicAdd(&cur[v >> 17], 1);
        csr[pos] = v & 0x1FFFF;
    }
}

// G[row][j] = bf16( dinv[row] * sum_k X[row][k]*W[k][j] )
// lane j owns output column j. W held in VGPRs in chunks of KC=16 (no spill);
// X tile staged in LDS, read back as wave-uniform float4 broadcasts.
template <int K, int RPW, int KC>
__global__ __launch_bounds__(256) void gemm_dinv(const float* __restrict__ X,
                                                 const float* __restrict__ W,
                                                 const float* __restrict__ dinv,
                                                 u16* __restrict__ G, int N) {
    constexpr int ROWS = 4 * RPW;
    __shared__ float Xl[ROWS * K];
    int lane = threadIdx.x & 63;
    int wid  = threadIdx.x >> 6;
    int row0 = blockIdx.x * ROWS;
    const float* xsrc = X + (size_t)row0 * K;

    if (row0 + ROWS <= N) {
#pragma unroll
        for (int i = threadIdx.x; i < ROWS * K / 4; i += 256)
            ((float4*)Xl)[i] = ((const float4*)xsrc)[i];
    } else {
        int avail = (N - row0) * K;
        for (int i = threadIdx.x; i < ROWS * K; i += 256)
            Xl[i] = (i < avail) ? xsrc[i] : 0.f;
    }
    __syncthreads();

    float acc[RPW];
#pragma unroll
    for (int r = 0; r < RPW; r++) acc[r] = 0.f;
    int rbase = wid * RPW;

#pragma unroll 1  // chunks sequential: only one w[KC] live at a time
    for (int c = 0; c < K / KC; c++) {
        float w[KC];
#pragma unroll
        for (int k = 0; k < KC; k++) w[k] = W[(c * KC + k) * 64 + lane];
#pragma unroll
        for (int r = 0; r < RPW; r++) {
            const float* xrow = &Xl[(rbase + r) * K + c * KC];
#pragma unroll
            for (int k4 = 0; k4 < KC / 4; k4++) {
                float4 xv = *(const float4*)&xrow[k4 * 4];  // wave-uniform broadcast
                acc[r] = fmaf(xv.x, w[k4 * 4 + 0], acc[r]);
                acc[r] = fmaf(xv.y, w[k4 * 4 + 1], acc[r]);
                acc[r] = fmaf(xv.z, w[k4 * 4 + 2], acc[r]);
                acc[r] = fmaf(xv.w, w[k4 * 4 + 3], acc[r]);
            }
        }
    }
#pragma unroll
    for (int r = 0; r < RPW; r++) {
        int row = row0 + rbase + r;
        if (row < N) G[(size_t)row * 64 + lane] = f2bf(dinv[row] * acc[r]);
    }
}

// H[node] = relu(dinv[node] * (G[node] + sum_{src} G[src]) + b), G is bf16.
// wave = 1 node; 8 groups x 8 lanes; lane loads uint4 (16B, 8 bf16 cols) so
// one wave instruction covers 8 full 128B rows; 4x unroll = 32 rows in flight.
// lo accs = even cols (bits<<16), hi accs = odd cols (bits&0xffff0000).
__global__ __launch_bounds__(256) void aggregate(const u16* __restrict__ G,
                                                 const int* __restrict__ rp,
                                                 const int* __restrict__ csr,
                                                 const float* __restrict__ dinv,
                                                 const float* __restrict__ bias,
                                                 float* __restrict__ H, int N) {
    int node = blockIdx.x * 4 + (threadIdx.x >> 6);
    if (node >= N) return;
    node = __builtin_amdgcn_readfirstlane(node);
    int lane = threadIdx.x & 63;
    int grp = lane >> 3, sub = lane & 7;
    int beg = rp[node], end = rp[node + 1];
    const uint4* Gr = (const uint4*)G;  // 8 uint4 per row

    float4 lo = make_float4(0.f, 0.f, 0.f, 0.f);
    float4 hi = make_float4(0.f, 0.f, 0.f, 0.f);
    if (grp == 0) addrow(Gr[(size_t)node * 8 + sub], lo, hi);  // self loop

    int e = beg + grp;
    for (; e + 24 < end; e += 32) {
        int s0 = csr[e], s1 = csr[e + 8], s2 = csr[e + 16], s3 = csr[e + 24];
        uint4 v0 = Gr[(size_t)s0 * 8 + sub];
        uint4 v1 = Gr[(size_t)s1 * 8 + sub];
        uint4 v2 = Gr[(size_t)s2 * 8 + sub];
        uint4 v3 = Gr[(size_t)s3 * 8 + sub];
        addrow(v0, lo, hi); addrow(v1, lo, hi);
        addrow(v2, lo, hi); addrow(v3, lo, hi);
    }
    for (; e < end; e += 8)
        addrow(Gr[(size_t)csr[e] * 8 + sub], lo, hi);

#pragma unroll
    for (int m = 8; m <= 32; m <<= 1) {
        lo.x += __shfl_xor(lo.x, m, 64); lo.y += __shfl_xor(lo.y, m, 64);
        lo.z += __shfl_xor(lo.z, m, 64); lo.w += __shfl_xor(lo.w, m, 64);
        hi.x += __shfl_xor(hi.x, m, 64); hi.y += __shfl_xor(hi.y, m, 64);
        hi.z += __shfl_xor(hi.z, m, 64); hi.w += __shfl_xor(hi.w, m, 64);
    }
    if (grp == 0) {
        float dn = dinv[node];
        float4 ba = ((const float4*)bias)[sub * 2];
        float4 bb = ((const float4*)bias)[sub * 2 + 1];
        float4 r0, r1;
        r0.x = fmaxf(fmaf(dn, lo.x, ba.x), 0.f);
        r0.y = fmaxf(fmaf(dn, hi.x, ba.y), 0.f);
        r0.z = fmaxf(fmaf(dn, lo.y, ba.z), 0.f);
        r0.w = fmaxf(fmaf(dn, hi.y, ba.w), 0.f);
        r1.x = fmaxf(fmaf(dn, lo.z, bb.x), 0.f);
        r1.y = fmaxf(fmaf(dn, hi.z, bb.y), 0.f);
        r1.z = fmaxf(fmaf(dn, lo.w, bb.z), 0.f);
        r1.w = fmaxf(fmaf(dn, hi.w, bb.w), 0.f);
        ((float4*)H)[(size_t)node * 16 + sub * 2]     = r0;
        ((float4*)H)[(size_t)node * 16 + sub * 2 + 1] = r1;
    }
}

// fused: block = 1 graph (256 threads, 4-way row parallel). binary-search
// [start,end) in sorted batch, mean-pool H rows, z=relu(p@Wc1+bc1), out=z@Wc2+bc2.
__global__ __launch_bounds__(256) void pool_classify(const float* __restrict__ H,
                                                     const int* __restrict__ batch,
                                                     const float* __restrict__ Wc1,
                                                     const float* __restrict__ bc1,
                                                     const float* __restrict__ Wc2,
                                                     const float* __restrict__ bc2,
                                                     float* __restrict__ out,
                                                     int N) {
    int g = blockIdx.x;
    int t = threadIdx.x & 63;
    int w = threadIdx.x >> 6;
    __shared__ float psum[4][64];
    __shared__ float p[64];
    __shared__ float z[32];

    int lo = 0, hi = N;
    while (lo < hi) { int m = (lo + hi) >> 1; if (batch[m] < g) lo = m + 1; else hi = m; }
    int start = lo;
    int lo2 = start, hi2 = N;
    while (lo2 < hi2) { int m = (lo2 + hi2) >> 1; if (batch[m] < g + 1) lo2 = m + 1; else hi2 = m; }
    int end = lo2;

    float acc = 0.f;
    for (int n = start + w; n < end; n += 4) acc += H[(size_t)n * 64 + t];
    psum[w][t] = acc;
    __syncthreads();
    if (w == 0) {
        float inv = 1.0f / fmaxf((float)(end - start), 1.0f);
        p[t] = (psum[0][t] + psum[1][t] + psum[2][t] + psum[3][t]) * inv;
    }
    __syncthreads();
    if (threadIdx.x < 32) {
        float a = bc1[threadIdx.x];
        for (int f = 0; f < 64; f++) a = fmaf(p[f], Wc1[f * 32 + threadIdx.x], a);
        z[threadIdx.x] = fmaxf(a, 0.f);
    }
    __syncthreads();
    if (threadIdx.x < 10) {
        float a = bc2[threadIdx.x];
        for (int j = 0; j < 32; j++) a = fmaf(z[j], Wc2[j * 10 + threadIdx.x], a);
        out[(size_t)g * 10 + threadIdx.x] = a;
    }
}

extern "C" void kernel_launch(void* const* d_in, const int* in_sizes, int n_in,
                              void* d_out, int out_size, void* d_ws, size_t ws_size,
                              hipStream_t stream) {
    const float* x   = (const float*)d_in[0];
    const int*   ei  = (const int*)d_in[1];
    const int*   bat = (const int*)d_in[2];
    const float* W1  = (const float*)d_in[3];
    const float* b1  = (const float*)d_in[4];
    const float* W2  = (const float*)d_in[5];
    const float* b2  = (const float*)d_in[6];
    const float* W3  = (const float*)d_in[7];
    const float* b3  = (const float*)d_in[8];
    const float* Wc1 = (const float*)d_in[9];
    const float* bc1 = (const float*)d_in[10];
    const float* Wc2 = (const float*)d_in[11];
    const float* bc2 = (const float*)d_in[12];

    const int N  = in_sizes[0] / 128;
    const int E  = in_sizes[1] / 2;
    const int NG = out_size / 10;
    const int B  = (N + 63) >> 6;  // <= BMAX for N <= 131072
    const int* srcp = ei;
    const int* dstp = ei + E;

    char* ws = (char*)d_ws;
    size_t off = 0;
    auto alloc = [&](size_t bytes) -> void* {
        void* p = ws + off;
        off += (bytes + 255) / 256 * 256;
        return p;
    };
    u16*   G      = (u16*)alloc((size_t)N * 64 * 2);   // bf16 gather table
    float* H      = (float*)alloc((size_t)N * 64 * 4);
    int*   pairs  = (int*)H;  // alias: pairs (E ints) dead before first aggregate writes H
    int*   csr    = (int*)alloc((size_t)E * 4);
    int*   rp     = (int*)alloc((size_t)(N + 1) * 4);
    float* dinv   = (float*)alloc((size_t)N * 4);
    int*   bcnt   = (int*)alloc((size_t)BMAX * 4);
    int*   prp    = (int*)alloc((size_t)(BMAX + 1) * 4);
    int*   cntmat = (int*)alloc((size_t)BMAX * NBLK * 4);  // 2 MB
    (void)ws_size; (void)n_in;

    // --- CSR build (two-level multisplit) ---
    const int chunk = (E + NBLK - 1) / NBLK;
    part_hist<<<NBLK, 1024, 0, stream>>>(dstp, cntmat, E, B, chunk);
    part_scan<<<(B + 3) / 4, 256, 0, stream>>>(cntmat, bcnt, B);
    bucket_scan<<<1, 256, 0, stream>>>(bcnt, prp, B);
    part_scatter<<<NBLK, 1024, 0, stream>>>(srcp, dstp, cntmat, prp, pairs, E, B, chunk);
    csr_build<<<B, 256, 0, stream>>>(pairs, prp, rp, dinv, csr, N, B, E);

    // --- 3 GCN layers: GEMM (bf16 G out) + pull-aggregate ---
    gemm_dinv<128, 8, 16><<<(N + 31) / 32, 256, 0, stream>>>(x, W1, dinv, G, N);
    aggregate<<<(N + 3) / 4, 256, 0, stream>>>(G, rp, csr, dinv, b1, H, N);
    gemm_dinv<64, 8, 16><<<(N + 31) / 32, 256, 0, stream>>>(H, W2, dinv, G, N);
    aggregate<<<(N + 3) / 4, 256, 0, stream>>>(G, rp, csr, dinv, b2, H, N);
    gemm_dinv<64, 8, 16><<<(N + 31) / 32, 256, 0, stream>>>(H, W3, dinv, G, N);
    aggregate<<<(N + 3) / 4, 256, 0, stream>>>(G, rp, csr, dinv, b3, H, N);

    // --- fused mean-pool + classifier ---
    pool_classify<<<NG, 256, 0, stream>>>(H, bat, Wc1, bc1, Wc2, bc2, (float*)d_out, N);
}

// Round 11
// 472.597 us; speedup vs baseline: 5.1335x; 1.0415x over previous
//
#include <hip/hip_runtime.h>
#include <hip/hip_bf16.h>

// GCN forward. CSR build via two-level multisplit (radix-partition style):
//   part_hist -> part_scan -> bucket_scan -> part_scatter (single-writer
//   cachelines per block -> write-combining) -> csr_build.
// Then 3x (GEMM -> pull-aggregate -> ReLU), fused mean-pool+MLP classifier.
// norm = dinv[src]*dinv[dst] factored into GEMM / aggregate epilogues.
// G (gather table) BF16 (12.8MB): halved gather bytes (r9).
// GEMM v3 (r10): old broadcast layout was LDS-issue-bound (1 ds_read_b128 :
// 4 FMA = 12:8 cyc, VALU 48%, 62us). New: lane=(rowhalf,colpair), 2 cols/lane
// -> 1 ds_read : 8 FMA, float2 W loads, packed bf16x2 dword stores.
// GEMM history: w[128]/w[64] spilled (r3/r7); KC=16 fit; now w=float2[16].
// Scatter history: naive 195MB/270us; shared-window 163MB/247us (XCD L2
// ping-pong); multisplit single-writer windows fixed it.
// Aggregate: 8 groups x 8 lanes, uint4 row loads; 4/2/1-deep unroll ladder.

typedef unsigned short u16;

__device__ __forceinline__ u16 f2bf(float f) {
    unsigned int x = __float_as_uint(f);
    return (u16)((x + 0x7fffu + ((x >> 16) & 1u)) >> 16);  // RNE
}
// add a dword-pair of bf16 (lo=bits<<16, hi=bits&0xffff0000) into lo/hi accs
__device__ __forceinline__ void addrow(const uint4 v, float4& lo, float4& hi) {
    lo.x += __uint_as_float(v.x << 16); hi.x += __uint_as_float(v.x & 0xffff0000u);
    lo.y += __uint_as_float(v.y << 16); hi.y += __uint_as_float(v.y & 0xffff0000u);
    lo.z += __uint_as_float(v.z << 16); hi.z += __uint_as_float(v.z & 0xffff0000u);
    lo.w += __uint_as_float(v.w << 16); hi.w += __uint_as_float(v.w & 0xffff0000u);
}

#define BMAX 2048  // buckets = ceil(N/64); N <= 131072
#define NBLK 256   // partition blocks (cntmat inner dim)

__global__ __launch_bounds__(1024) void part_hist(const int* __restrict__ dst,
                                                  int* __restrict__ cntmat,
                                                  int E, int B, int chunk) {
    __shared__ int hist[BMAX];
    for (int i = threadIdx.x; i < BMAX; i += 1024) hist[i] = 0;
    __syncthreads();
    int s = blockIdx.x * chunk;
    int en = min(s + chunk, E);
    for (int i = s + threadIdx.x; i < en; i += 1024)
        atomicAdd(&hist[dst[i] >> 6], 1);
    __syncthreads();
    for (int i = threadIdx.x; i < B; i += 1024)
        cntmat[i * NBLK + blockIdx.x] = hist[i];
}

// one wave per bucket: exclusive scan of cntmat[b][0..256) in 4x64 chunks.
__global__ __launch_bounds__(256) void part_scan(int* __restrict__ cntmat,
                                                 int* __restrict__ bcnt, int B) {
    int w = threadIdx.x >> 6;
    int lane = threadIdx.x & 63;
    int b = blockIdx.x * 4 + w;
    if (b >= B) return;
    int carry = 0;
#pragma unroll
    for (int j = 0; j < NBLK / 64; j++) {
        int idx = b * NBLK + j * 64 + lane;
        int v = cntmat[idx];
        int x = v;
#pragma unroll
        for (int d = 1; d < 64; d <<= 1) {
            int t = __shfl_up(x, d, 64);
            if (lane >= d) x += t;
        }
        cntmat[idx] = x - v + carry;          // exclusive within bucket
        carry += __shfl(x, 63, 64);           // add chunk total
    }
    if (lane == 0) bcnt[b] = carry;
}

// single block: exclusive scan of bcnt[0..M) -> prp (bucket starts).
__global__ __launch_bounds__(256) void bucket_scan(const int* __restrict__ bcnt,
                                                   int* __restrict__ prp, int M) {
    __shared__ int lds[256];
    int t = threadIdx.x;
    int base = t * 8;
    int v[8]; int ts = 0;
#pragma unroll
    for (int i = 0; i < 8; i++) { int idx = base + i; int x = (idx < M) ? bcnt[idx] : 0; v[i] = x; ts += x; }
    lds[t] = ts; __syncthreads();
#pragma unroll
    for (int d = 1; d < 256; d <<= 1) {
        int x = (t >= d) ? lds[t - d] : 0; __syncthreads();
        lds[t] += x; __syncthreads();
    }
    int run = lds[t] - ts;
#pragma unroll
    for (int i = 0; i < 8; i++) {
        int idx = base + i;
        if (idx < M) { prp[idx] = run; run += v[i]; }
    }
    if (t == 255) prp[M] = lds[255];  // == E
}

// pairs[pos] = src | (dst&63)<<17 (src < 2^17). Each block owns exclusive
// contiguous runs per bucket -> single-writer cachelines.
__global__ __launch_bounds__(1024) void part_scatter(const int* __restrict__ src,
                                                     const int* __restrict__ dst,
                                                     const int* __restrict__ cntmat,
                                                     const int* __restrict__ prp,
                                                     int* __restrict__ pairs,
                                                     int E, int B, int chunk) {
    __shared__ int cur[BMAX];
    for (int i = threadIdx.x; i < B; i += 1024)
        cur[i] = prp[i] + cntmat[i * NBLK + blockIdx.x];
    __syncthreads();
    int s = blockIdx.x * chunk;
    int en = min(s + chunk, E);
    for (int i = s + threadIdx.x; i < en; i += 1024) {
        int d = dst[i];
        int pos = atomicAdd(&cur[d >> 6], 1);
        pairs[pos] = src[i] | ((d & 63) << 17);
    }
}

// one block per bucket: local hist -> rp, dinv, csr.
__global__ __launch_bounds__(256) void csr_build(const int* __restrict__ pairs,
                                                 const int* __restrict__ prp,
                                                 int* __restrict__ rp,
                                                 float* __restrict__ dinv,
                                                 int* __restrict__ csr,
                                                 int N, int B, int E) {
    __shared__ int hist[64], cur[64];
    int b = blockIdx.x;
    int t = threadIdx.x;
    if (t < 64) hist[t] = 0;
    __syncthreads();
    int r0 = prp[b], r1 = prp[b + 1];
    for (int i = r0 + t; i < r1; i += 256)
        atomicAdd(&hist[pairs[i] >> 17], 1);
    __syncthreads();
    if (t == 0) {
        int run = r0;
        for (int k = 0; k < 64; k++) { cur[k] = run; run += hist[k]; }
    }
    __syncthreads();
    if (t < 64) {
        int node = b * 64 + t;
        if (node < N) {
            rp[node] = cur[t];
            dinv[node] = rsqrtf((float)(hist[t] + 1));  // +1 self loop
        }
    }
    if (b == B - 1 && t == 0) rp[N] = E;
    __syncthreads();
    for (int i = r0 + t; i < r1; i += 256) {
        int v = pairs[i];
        int pos = atomicAdd(&cur[v >> 17], 1);
        csr[pos] = v & 0x1FFFF;
    }
}

// G[row][j] = bf16( dinv[row] * sum_k X[row][k]*W[k][j] ), packed 2 cols/dword.
// lane = (rh, c): cols {2c,2c+1}, rows wid*16 + 2p + rh. One ds_read_b128
// (4 x-vals, wave has only 2 distinct addrs -> free broadcast) feeds 8 FMAs.
// W loaded as float2 (coalesced); 64 rows/block staged in LDS.
template <int K>
__global__ __launch_bounds__(256) void gemm_dinv(const float* __restrict__ X,
                                                 const float* __restrict__ W,
                                                 const float* __restrict__ dinv,
                                                 unsigned int* __restrict__ G2, int N) {
    constexpr int ROWS = 64;
    __shared__ float Xl[ROWS * K];
    int tid = threadIdx.x;
    int c   = tid & 31;        // column pair index: cols 2c, 2c+1
    int rh  = (tid >> 5) & 1;  // row half within pass
    int wid = tid >> 6;
    int row0 = blockIdx.x * ROWS;
    const float* xsrc = X + (size_t)row0 * K;

    if (row0 + ROWS <= N) {
#pragma unroll
        for (int i = tid; i < ROWS * K / 4; i += 256)
            ((float4*)Xl)[i] = ((const float4*)xsrc)[i];
    } else {
        int avail = (N - row0) * K;
        for (int i = tid; i < ROWS * K; i += 256)
            Xl[i] = (i < avail) ? xsrc[i] : 0.f;
    }
    __syncthreads();

    float2 acc[8];
#pragma unroll
    for (int p = 0; p < 8; p++) { acc[p].x = 0.f; acc[p].y = 0.f; }
    const float2* W2 = (const float2*)W;

#pragma unroll 1  // chunks sequential: one w[16] live at a time (no spill)
    for (int ck = 0; ck < K / 16; ck++) {
        float2 w[16];
#pragma unroll
        for (int k = 0; k < 16; k++) w[k] = W2[(ck * 16 + k) * 32 + c];
#pragma unroll
        for (int p = 0; p < 8; p++) {
            const float* xrow = &Xl[(wid * 16 + p * 2 + rh) * K + ck * 16];
#pragma unroll
            for (int k4 = 0; k4 < 4; k4++) {
                float4 xv = *(const float4*)&xrow[k4 * 4];
                acc[p].x = fmaf(xv.x, w[k4 * 4 + 0].x, acc[p].x);
                acc[p].y = fmaf(xv.x, w[k4 * 4 + 0].y, acc[p].y);
                acc[p].x = fmaf(xv.y, w[k4 * 4 + 1].x, acc[p].x);
                acc[p].y = fmaf(xv.y, w[k4 * 4 + 1].y, acc[p].y);
                acc[p].x = fmaf(xv.z, w[k4 * 4 + 2].x, acc[p].x);
                acc[p].y = fmaf(xv.z, w[k4 * 4 + 2].y, acc[p].y);
                acc[p].x = fmaf(xv.w, w[k4 * 4 + 3].x, acc[p].x);
                acc[p].y = fmaf(xv.w, w[k4 * 4 + 3].y, acc[p].y);
            }
        }
    }
#pragma unroll
    for (int p = 0; p < 8; p++) {
        int row = row0 + wid * 16 + p * 2 + rh;
        if (row < N) {
            float dn = dinv[row];
            unsigned int lo = f2bf(dn * acc[p].x);
            unsigned int hi = f2bf(dn * acc[p].y);
            G2[(size_t)row * 32 + c] = lo | (hi << 16);
        }
    }
}

// H[node] = relu(dinv[node] * (G[node] + sum_{src} G[src]) + b), G is bf16.
// wave = 1 node; 8 groups x 8 lanes; lane loads uint4 (16B, 8 bf16 cols) so
// one wave instruction covers 8 full 128B rows; 4/2/1-deep unroll ladder.
__global__ __launch_bounds__(256) void aggregate(const unsigned int* __restrict__ G,
                                                 const int* __restrict__ rp,
                                                 const int* __restrict__ csr,
                                                 const float* __restrict__ dinv,
                                                 const float* __restrict__ bias,
                                                 float* __restrict__ H, int N) {
    int node = blockIdx.x * 4 + (threadIdx.x >> 6);
    if (node >= N) return;
    node = __builtin_amdgcn_readfirstlane(node);
    int lane = threadIdx.x & 63;
    int grp = lane >> 3, sub = lane & 7;
    int beg = rp[node], end = rp[node + 1];
    const uint4* Gr = (const uint4*)G;  // 8 uint4 per row

    float4 lo = make_float4(0.f, 0.f, 0.f, 0.f);
    float4 hi = make_float4(0.f, 0.f, 0.f, 0.f);
    if (grp == 0) addrow(Gr[(size_t)node * 8 + sub], lo, hi);  // self loop

    int e = beg + grp;
    for (; e + 24 < end; e += 32) {
        int s0 = csr[e], s1 = csr[e + 8], s2 = csr[e + 16], s3 = csr[e + 24];
        uint4 v0 = Gr[(size_t)s0 * 8 + sub];
        uint4 v1 = Gr[(size_t)s1 * 8 + sub];
        uint4 v2 = Gr[(size_t)s2 * 8 + sub];
        uint4 v3 = Gr[(size_t)s3 * 8 + sub];
        addrow(v0, lo, hi); addrow(v1, lo, hi);
        addrow(v2, lo, hi); addrow(v3, lo, hi);
    }
    if (e + 8 < end) {
        int s0 = csr[e], s1 = csr[e + 8];
        uint4 v0 = Gr[(size_t)s0 * 8 + sub];
        uint4 v1 = Gr[(size_t)s1 * 8 + sub];
        addrow(v0, lo, hi); addrow(v1, lo, hi);
        e += 16;
    }
    for (; e < end; e += 8)
        addrow(Gr[(size_t)csr[e] * 8 + sub], lo, hi);

#pragma unroll
    for (int m = 8; m <= 32; m <<= 1) {
        lo.x += __shfl_xor(lo.x, m, 64); lo.y += __shfl_xor(lo.y, m, 64);
        lo.z += __shfl_xor(lo.z, m, 64); lo.w += __shfl_xor(lo.w, m, 64);
        hi.x += __shfl_xor(hi.x, m, 64); hi.y += __shfl_xor(hi.y, m, 64);
        hi.z += __shfl_xor(hi.z, m, 64); hi.w += __shfl_xor(hi.w, m, 64);
    }
    if (grp == 0) {
        float dn = dinv[node];
        float4 ba = ((const float4*)bias)[sub * 2];
        float4 bb = ((const float4*)bias)[sub * 2 + 1];
        float4 r0, r1;
        r0.x = fmaxf(fmaf(dn, lo.x, ba.x), 0.f);
        r0.y = fmaxf(fmaf(dn, hi.x, ba.y), 0.f);
        r0.z = fmaxf(fmaf(dn, lo.y, ba.z), 0.f);
        r0.w = fmaxf(fmaf(dn, hi.y, ba.w), 0.f);
        r1.x = fmaxf(fmaf(dn, lo.z, bb.x), 0.f);
        r1.y = fmaxf(fmaf(dn, hi.z, bb.y), 0.f);
        r1.z = fmaxf(fmaf(dn, lo.w, bb.z), 0.f);
        r1.w = fmaxf(fmaf(dn, hi.w, bb.w), 0.f);
        ((float4*)H)[(size_t)node * 16 + sub * 2]     = r0;
        ((float4*)H)[(size_t)node * 16 + sub * 2 + 1] = r1;
    }
}

// fused: block = 1 graph (256 threads, 4-way row parallel). binary-search
// [start,end) in sorted batch, mean-pool H rows, z=relu(p@Wc1+bc1), out=z@Wc2+bc2.
__global__ __launch_bounds__(256) void pool_classify(const float* __restrict__ H,
                                                     const int* __restrict__ batch,
                                                     const float* __restrict__ Wc1,
                                                     const float* __restrict__ bc1,
                                                     const float* __restrict__ Wc2,
                                                     const float* __restrict__ bc2,
                                                     float* __restrict__ out,
                                                     int N) {
    int g = blockIdx.x;
    int t = threadIdx.x & 63;
    int w = threadIdx.x >> 6;
    __shared__ float psum[4][64];
    __shared__ float p[64];
    __shared__ float z[32];

    int lo = 0, hi = N;
    while (lo < hi) { int m = (lo + hi) >> 1; if (batch[m] < g) lo = m + 1; else hi = m; }
    int start = lo;
    int lo2 = start, hi2 = N;
    while (lo2 < hi2) { int m = (lo2 + hi2) >> 1; if (batch[m] < g + 1) lo2 = m + 1; else hi2 = m; }
    int end = lo2;

    float acc = 0.f;
    for (int n = start + w; n < end; n += 4) acc += H[(size_t)n * 64 + t];
    psum[w][t] = acc;
    __syncthreads();
    if (w == 0) {
        float inv = 1.0f / fmaxf((float)(end - start), 1.0f);
        p[t] = (psum[0][t] + psum[1][t] + psum[2][t] + psum[3][t]) * inv;
    }
    __syncthreads();
    if (threadIdx.x < 32) {
        float a = bc1[threadIdx.x];
        for (int f = 0; f < 64; f++) a = fmaf(p[f], Wc1[f * 32 + threadIdx.x], a);
        z[threadIdx.x] = fmaxf(a, 0.f);
    }
    __syncthreads();
    if (threadIdx.x < 10) {
        float a = bc2[threadIdx.x];
        for (int j = 0; j < 32; j++) a = fmaf(z[j], Wc2[j * 10 + threadIdx.x], a);
        out[(size_t)g * 10 + threadIdx.x] = a;
    }
}

extern "C" void kernel_launch(void* const* d_in, const int* in_sizes, int n_in,
                              void* d_out, int out_size, void* d_ws, size_t ws_size,
                              hipStream_t stream) {
    const float* x   = (const float*)d_in[0];
    const int*   ei  = (const int*)d_in[1];
    const int*   bat = (const int*)d_in[2];
    const float* W1  = (const float*)d_in[3];
    const float* b1  = (const float*)d_in[4];
    const float* W2  = (const float*)d_in[5];
    const float* b2  = (const float*)d_in[6];
    const float* W3  = (const float*)d_in[7];
    const float* b3  = (const float*)d_in[8];
    const float* Wc1 = (const float*)d_in[9];
    const float* bc1 = (const float*)d_in[10];
    const float* Wc2 = (const float*)d_in[11];
    const float* bc2 = (const float*)d_in[12];

    const int N  = in_sizes[0] / 128;
    const int E  = in_sizes[1] / 2;
    const int NG = out_size / 10;
    const int B  = (N + 63) >> 6;  // <= BMAX for N <= 131072
    const int* srcp = ei;
    const int* dstp = ei + E;

    char* ws = (char*)d_ws;
    size_t off = 0;
    auto alloc = [&](size_t bytes) -> void* {
        void* p = ws + off;
        off += (bytes + 255) / 256 * 256;
        return p;
    };
    unsigned int* G = (unsigned int*)alloc((size_t)N * 32 * 4);  // bf16x2 gather table
    float* H      = (float*)alloc((size_t)N * 64 * 4);
    int*   pairs  = (int*)H;  // alias: pairs (E ints) dead before first aggregate writes H
    int*   csr    = (int*)alloc((size_t)E * 4);
    int*   rp     = (int*)alloc((size_t)(N + 1) * 4);
    float* dinv   = (float*)alloc((size_t)N * 4);
    int*   bcnt   = (int*)alloc((size_t)BMAX * 4);
    int*   prp    = (int*)alloc((size_t)(BMAX + 1) * 4);
    int*   cntmat = (int*)alloc((size_t)BMAX * NBLK * 4);  // 2 MB
    (void)ws_size; (void)n_in;

    // --- CSR build (two-level multisplit) ---
    const int chunk = (E + NBLK - 1) / NBLK;
    part_hist<<<NBLK, 1024, 0, stream>>>(dstp, cntmat, E, B, chunk);
    part_scan<<<(B + 3) / 4, 256, 0, stream>>>(cntmat, bcnt, B);
    bucket_scan<<<1, 256, 0, stream>>>(bcnt, prp, B);
    part_scatter<<<NBLK, 1024, 0, stream>>>(srcp, dstp, cntmat, prp, pairs, E, B, chunk);
    csr_build<<<B, 256, 0, stream>>>(pairs, prp, rp, dinv, csr, N, B, E);

    // --- 3 GCN layers: GEMM (bf16x2-packed G out) + pull-aggregate ---
    gemm_dinv<128><<<(N + 63) / 64, 256, 0, stream>>>(x, W1, dinv, G, N);
    aggregate<<<(N + 3) / 4, 256, 0, stream>>>(G, rp, csr, dinv, b1, H, N);
    gemm_dinv<64><<<(N + 63) / 64, 256, 0, stream>>>(H, W2, dinv, G, N);
    aggregate<<<(N + 3) / 4, 256, 0, stream>>>(G, rp, csr, dinv, b2, H, N);
    gemm_dinv<64><<<(N + 63) / 64, 256, 0, stream>>>(H, W3, dinv, G, N);
    aggregate<<<(N + 3) / 4, 256, 0, stream>>>(G, rp, csr, dinv, b3, H, N);

    // --- fused mean-pool + classifier ---
    pool_classify<<<NG, 256, 0, stream>>>(H, bat, Wc1, bc1, Wc2, bc2, (float*)d_out, N);
}

// Round 12
// 456.389 us; speedup vs baseline: 5.3158x; 1.0355x over previous
//
#include <hip/hip_runtime.h>
#include <hip/hip_bf16.h>

// GCN forward. CSR build via two-level multisplit (radix-partition style):
//   part_hist -> part_scan -> bucket_scan -> part_scatter (single-writer
//   cachelines per block -> write-combining) -> csr_build.
// Then 3x (GEMM -> pull-aggregate -> ReLU), fused mean-pool+MLP classifier.
// norm = dinv[src]*dinv[dst] factored into GEMM / aggregate epilogues.
// G (gather table) BF16 (12.8MB): halved gather bytes (r9).
// Aggregate v3 (r12): r11 showed VALU 51% co-dominant with mem. Per-dword
// unpack now shl+and into a VGPR pair + one v_pk_add_f32 (full-rate packed
// f32, CDNA2+), and G loads use 32-bit byte offsets (saddr+voffset form).
// GEMM v3 (r10): lane=(rowhalf,colpair), 2 cols/lane -> 1 ds_read : 8 FMA.
// GEMM history: w[128]/w[64] spilled (r3/r7); KC=16 fit; now w=float2[16].
// Scatter history: naive 195MB/270us; shared-window 163MB/247us (XCD L2
// ping-pong); multisplit single-writer windows fixed it.

typedef unsigned short u16;
typedef float f32x2 __attribute__((ext_vector_type(2)));

__device__ __forceinline__ u16 f2bf(float f) {
    unsigned int x = __float_as_uint(f);
    return (u16)((x + 0x7fffu + ((x >> 16) & 1u)) >> 16);  // RNE
}

// p += {bf16lo(v), bf16hi(v)} via one packed-f32 add (full rate on CDNA4)
__device__ __forceinline__ void pk_acc(f32x2& p, unsigned int v) {
    f32x2 u;
    u[0] = __uint_as_float(v << 16);
    u[1] = __uint_as_float(v & 0xffff0000u);
    asm("v_pk_add_f32 %0, %0, %1" : "+v"(p) : "v"(u));
}
__device__ __forceinline__ void addrow_pk(const uint4 v, f32x2& p0, f32x2& p1,
                                          f32x2& p2, f32x2& p3) {
    pk_acc(p0, v.x); pk_acc(p1, v.y); pk_acc(p2, v.z); pk_acc(p3, v.w);
}

#define BMAX 2048  // buckets = ceil(N/64); N <= 131072
#define NBLK 256   // partition blocks (cntmat inner dim)

__global__ __launch_bounds__(1024) void part_hist(const int* __restrict__ dst,
                                                  int* __restrict__ cntmat,
                                                  int E, int B, int chunk) {
    __shared__ int hist[BMAX];
    for (int i = threadIdx.x; i < BMAX; i += 1024) hist[i] = 0;
    __syncthreads();
    int s = blockIdx.x * chunk;
    int en = min(s + chunk, E);
    for (int i = s + threadIdx.x; i < en; i += 1024)
        atomicAdd(&hist[dst[i] >> 6], 1);
    __syncthreads();
    for (int i = threadIdx.x; i < B; i += 1024)
        cntmat[i * NBLK + blockIdx.x] = hist[i];
}

// one wave per bucket: exclusive scan of cntmat[b][0..256) in 4x64 chunks.
__global__ __launch_bounds__(256) void part_scan(int* __restrict__ cntmat,
                                                 int* __restrict__ bcnt, int B) {
    int w = threadIdx.x >> 6;
    int lane = threadIdx.x & 63;
    int b = blockIdx.x * 4 + w;
    if (b >= B) return;
    int carry = 0;
#pragma unroll
    for (int j = 0; j < NBLK / 64; j++) {
        int idx = b * NBLK + j * 64 + lane;
        int v = cntmat[idx];
        int x = v;
#pragma unroll
        for (int d = 1; d < 64; d <<= 1) {
            int t = __shfl_up(x, d, 64);
            if (lane >= d) x += t;
        }
        cntmat[idx] = x - v + carry;          // exclusive within bucket
        carry += __shfl(x, 63, 64);           // add chunk total
    }
    if (lane == 0) bcnt[b] = carry;
}

// single block: exclusive scan of bcnt[0..M) -> prp (bucket starts).
__global__ __launch_bounds__(256) void bucket_scan(const int* __restrict__ bcnt,
                                                   int* __restrict__ prp, int M) {
    __shared__ int lds[256];
    int t = threadIdx.x;
    int base = t * 8;
    int v[8]; int ts = 0;
#pragma unroll
    for (int i = 0; i < 8; i++) { int idx = base + i; int x = (idx < M) ? bcnt[idx] : 0; v[i] = x; ts += x; }
    lds[t] = ts; __syncthreads();
#pragma unroll
    for (int d = 1; d < 256; d <<= 1) {
        int x = (t >= d) ? lds[t - d] : 0; __syncthreads();
        lds[t] += x; __syncthreads();
    }
    int run = lds[t] - ts;
#pragma unroll
    for (int i = 0; i < 8; i++) {
        int idx = base + i;
        if (idx < M) { prp[idx] = run; run += v[i]; }
    }
    if (t == 255) prp[M] = lds[255];  // == E
}

// pairs[pos] = src | (dst&63)<<17 (src < 2^17). Each block owns exclusive
// contiguous runs per bucket -> single-writer cachelines.
__global__ __launch_bounds__(1024) void part_scatter(const int* __restrict__ src,
                                                     const int* __restrict__ dst,
                                                     const int* __restrict__ cntmat,
                                                     const int* __restrict__ prp,
                                                     int* __restrict__ pairs,
                                                     int E, int B, int chunk) {
    __shared__ int cur[BMAX];
    for (int i = threadIdx.x; i < B; i += 1024)
        cur[i] = prp[i] + cntmat[i * NBLK + blockIdx.x];
    __syncthreads();
    int s = blockIdx.x * chunk;
    int en = min(s + chunk, E);
    for (int i = s + threadIdx.x; i < en; i += 1024) {
        int d = dst[i];
        int pos = atomicAdd(&cur[d >> 6], 1);
        pairs[pos] = src[i] | ((d & 63) << 17);
    }
}

// one block per bucket: local hist -> rp, dinv, csr.
__global__ __launch_bounds__(256) void csr_build(const int* __restrict__ pairs,
                                                 const int* __restrict__ prp,
                                                 int* __restrict__ rp,
                                                 float* __restrict__ dinv,
                                                 int* __restrict__ csr,
                                                 int N, int B, int E) {
    __shared__ int hist[64], cur[64];
    int b = blockIdx.x;
    int t = threadIdx.x;
    if (t < 64) hist[t] = 0;
    __syncthreads();
    int r0 = prp[b], r1 = prp[b + 1];
    for (int i = r0 + t; i < r1; i += 256)
        atomicAdd(&hist[pairs[i] >> 17], 1);
    __syncthreads();
    if (t == 0) {
        int run = r0;
        for (int k = 0; k < 64; k++) { cur[k] = run; run += hist[k]; }
    }
    __syncthreads();
    if (t < 64) {
        int node = b * 64 + t;
        if (node < N) {
            rp[node] = cur[t];
            dinv[node] = rsqrtf((float)(hist[t] + 1));  // +1 self loop
        }
    }
    if (b == B - 1 && t == 0) rp[N] = E;
    __syncthreads();
    for (int i = r0 + t; i < r1; i += 256) {
        int v = pairs[i];
        int pos = atomicAdd(&cur[v >> 17], 1);
        csr[pos] = v & 0x1FFFF;
    }
}

// G[row][j] = bf16( dinv[row] * sum_k X[row][k]*W[k][j] ), packed 2 cols/dword.
// lane = (rh, c): cols {2c,2c+1}, rows wid*16 + 2p + rh. One ds_read_b128
// (4 x-vals, wave has only 2 distinct addrs -> free broadcast) feeds 8 FMAs.
// W loaded as float2 (coalesced); 64 rows/block staged in LDS.
template <int K>
__global__ __launch_bounds__(256) void gemm_dinv(const float* __restrict__ X,
                                                 const float* __restrict__ W,
                                                 const float* __restrict__ dinv,
                                                 unsigned int* __restrict__ G2, int N) {
    constexpr int ROWS = 64;
    __shared__ float Xl[ROWS * K];
    int tid = threadIdx.x;
    int c   = tid & 31;        // column pair index: cols 2c, 2c+1
    int rh  = (tid >> 5) & 1;  // row half within pass
    int wid = tid >> 6;
    int row0 = blockIdx.x * ROWS;
    const float* xsrc = X + (size_t)row0 * K;

    if (row0 + ROWS <= N) {
#pragma unroll
        for (int i = tid; i < ROWS * K / 4; i += 256)
            ((float4*)Xl)[i] = ((const float4*)xsrc)[i];
    } else {
        int avail = (N - row0) * K;
        for (int i = tid; i < ROWS * K; i += 256)
            Xl[i] = (i < avail) ? xsrc[i] : 0.f;
    }
    __syncthreads();

    float2 acc[8];
#pragma unroll
    for (int p = 0; p < 8; p++) { acc[p].x = 0.f; acc[p].y = 0.f; }
    const float2* W2 = (const float2*)W;

#pragma unroll 1  // chunks sequential: one w[16] live at a time (no spill)
    for (int ck = 0; ck < K / 16; ck++) {
        float2 w[16];
#pragma unroll
        for (int k = 0; k < 16; k++) w[k] = W2[(ck * 16 + k) * 32 + c];
#pragma unroll
        for (int p = 0; p < 8; p++) {
            const float* xrow = &Xl[(wid * 16 + p * 2 + rh) * K + ck * 16];
#pragma unroll
            for (int k4 = 0; k4 < 4; k4++) {
                float4 xv = *(const float4*)&xrow[k4 * 4];
                acc[p].x = fmaf(xv.x, w[k4 * 4 + 0].x, acc[p].x);
                acc[p].y = fmaf(xv.x, w[k4 * 4 + 0].y, acc[p].y);
                acc[p].x = fmaf(xv.y, w[k4 * 4 + 1].x, acc[p].x);
                acc[p].y = fmaf(xv.y, w[k4 * 4 + 1].y, acc[p].y);
                acc[p].x = fmaf(xv.z, w[k4 * 4 + 2].x, acc[p].x);
                acc[p].y = fmaf(xv.z, w[k4 * 4 + 2].y, acc[p].y);
                acc[p].x = fmaf(xv.w, w[k4 * 4 + 3].x, acc[p].x);
                acc[p].y = fmaf(xv.w, w[k4 * 4 + 3].y, acc[p].y);
            }
        }
    }
#pragma unroll
    for (int p = 0; p < 8; p++) {
        int row = row0 + wid * 16 + p * 2 + rh;
        if (row < N) {
            float dn = dinv[row];
            unsigned int lo = f2bf(dn * acc[p].x);
            unsigned int hi = f2bf(dn * acc[p].y);
            G2[(size_t)row * 32 + c] = lo | (hi << 16);
        }
    }
}

// H[node] = relu(dinv[node] * (G[node] + sum_{src} G[src]) + b), G is bf16.
// wave = 1 node; 8 groups x 8 lanes; lane loads uint4 (16B, 8 bf16 cols) so
// one wave instruction covers 8 full 128B rows; 4/2/1-deep unroll ladder.
// Accumulators are f32x2 column pairs fed by v_pk_add_f32; G addressed with
// 32-bit byte offsets (base SGPR + voffset) to cut 64-bit address VALU.
__global__ __launch_bounds__(256) void aggregate(const unsigned int* __restrict__ G,
                                                 const int* __restrict__ rp,
                                                 const int* __restrict__ csr,
                                                 const float* __restrict__ dinv,
                                                 const float* __restrict__ bias,
                                                 float* __restrict__ H, int N) {
    int node = blockIdx.x * 4 + (threadIdx.x >> 6);
    if (node >= N) return;
    node = __builtin_amdgcn_readfirstlane(node);
    int lane = threadIdx.x & 63;
    int grp = lane >> 3, sub = lane & 7;
    int beg = rp[node], end = rp[node + 1];
    const char* Gb = (const char*)G;
    unsigned int so = (unsigned int)sub << 4;  // 16B per uint4

    f32x2 p0 = {0.f, 0.f}, p1 = {0.f, 0.f}, p2 = {0.f, 0.f}, p3 = {0.f, 0.f};
    if (grp == 0) {  // self loop
        uint4 v = *(const uint4*)(Gb + (((unsigned int)node << 7) + so));
        addrow_pk(v, p0, p1, p2, p3);
    }

    int e = beg + grp;
    for (; e + 24 < end; e += 32) {
        unsigned int o0 = ((unsigned int)csr[e] << 7) + so;
        unsigned int o1 = ((unsigned int)csr[e + 8] << 7) + so;
        unsigned int o2 = ((unsigned int)csr[e + 16] << 7) + so;
        unsigned int o3 = ((unsigned int)csr[e + 24] << 7) + so;
        uint4 v0 = *(const uint4*)(Gb + o0);
        uint4 v1 = *(const uint4*)(Gb + o1);
        uint4 v2 = *(const uint4*)(Gb + o2);
        uint4 v3 = *(const uint4*)(Gb + o3);
        addrow_pk(v0, p0, p1, p2, p3); addrow_pk(v1, p0, p1, p2, p3);
        addrow_pk(v2, p0, p1, p2, p3); addrow_pk(v3, p0, p1, p2, p3);
    }
    if (e + 8 < end) {
        unsigned int o0 = ((unsigned int)csr[e] << 7) + so;
        unsigned int o1 = ((unsigned int)csr[e + 8] << 7) + so;
        uint4 v0 = *(const uint4*)(Gb + o0);
        uint4 v1 = *(const uint4*)(Gb + o1);
        addrow_pk(v0, p0, p1, p2, p3); addrow_pk(v1, p0, p1, p2, p3);
        e += 16;
    }
    for (; e < end; e += 8) {
        uint4 v = *(const uint4*)(Gb + (((unsigned int)csr[e] << 7) + so));
        addrow_pk(v, p0, p1, p2, p3);
    }

#pragma unroll
    for (int m = 8; m <= 32; m <<= 1) {
        p0[0] += __shfl_xor(p0[0], m, 64); p0[1] += __shfl_xor(p0[1], m, 64);
        p1[0] += __shfl_xor(p1[0], m, 64); p1[1] += __shfl_xor(p1[1], m, 64);
        p2[0] += __shfl_xor(p2[0], m, 64); p2[1] += __shfl_xor(p2[1], m, 64);
        p3[0] += __shfl_xor(p3[0], m, 64); p3[1] += __shfl_xor(p3[1], m, 64);
    }
    if (grp == 0) {
        float dn = dinv[node];
        float4 ba = ((const float4*)bias)[sub * 2];
        float4 bb = ((const float4*)bias)[sub * 2 + 1];
        float4 r0, r1;
        r0.x = fmaxf(fmaf(dn, p0[0], ba.x), 0.f);
        r0.y = fmaxf(fmaf(dn, p0[1], ba.y), 0.f);
        r0.z = fmaxf(fmaf(dn, p1[0], ba.z), 0.f);
        r0.w = fmaxf(fmaf(dn, p1[1], ba.w), 0.f);
        r1.x = fmaxf(fmaf(dn, p2[0], bb.x), 0.f);
        r1.y = fmaxf(fmaf(dn, p2[1], bb.y), 0.f);
        r1.z = fmaxf(fmaf(dn, p3[0], bb.z), 0.f);
        r1.w = fmaxf(fmaf(dn, p3[1], bb.w), 0.f);
        ((float4*)H)[(size_t)node * 16 + sub * 2]     = r0;
        ((float4*)H)[(size_t)node * 16 + sub * 2 + 1] = r1;
    }
}

// fused: block = 1 graph (256 threads, 4-way row parallel). binary-search
// [start,end) in sorted batch, mean-pool H rows, z=relu(p@Wc1+bc1), out=z@Wc2+bc2.
__global__ __launch_bounds__(256) void pool_classify(const float* __restrict__ H,
                                                     const int* __restrict__ batch,
                                                     const float* __restrict__ Wc1,
                                                     const float* __restrict__ bc1,
                                                     const float* __restrict__ Wc2,
                                                     const float* __restrict__ bc2,
                                                     float* __restrict__ out,
                                                     int N) {
    int g = blockIdx.x;
    int t = threadIdx.x & 63;
    int w = threadIdx.x >> 6;
    __shared__ float psum[4][64];
    __shared__ float p[64];
    __shared__ float z[32];

    int lo = 0, hi = N;
    while (lo < hi) { int m = (lo + hi) >> 1; if (batch[m] < g) lo = m + 1; else hi = m; }
    int start = lo;
    int lo2 = start, hi2 = N;
    while (lo2 < hi2) { int m = (lo2 + hi2) >> 1; if (batch[m] < g + 1) lo2 = m + 1; else hi2 = m; }
    int end = lo2;

    float acc = 0.f;
    for (int n = start + w; n < end; n += 4) acc += H[(size_t)n * 64 + t];
    psum[w][t] = acc;
    __syncthreads();
    if (w == 0) {
        float inv = 1.0f / fmaxf((float)(end - start), 1.0f);
        p[t] = (psum[0][t] + psum[1][t] + psum[2][t] + psum[3][t]) * inv;
    }
    __syncthreads();
    if (threadIdx.x < 32) {
        float a = bc1[threadIdx.x];
        for (int f = 0; f < 64; f++) a = fmaf(p[f], Wc1[f * 32 + threadIdx.x], a);
        z[threadIdx.x] = fmaxf(a, 0.f);
    }
    __syncthreads();
    if (threadIdx.x < 10) {
        float a = bc2[threadIdx.x];
        for (int j = 0; j < 32; j++) a = fmaf(z[j], Wc2[j * 10 + threadIdx.x], a);
        out[(size_t)g * 10 + threadIdx.x] = a;
    }
}

extern "C" void kernel_launch(void* const* d_in, const int* in_sizes, int n_in,
                              void* d_out, int out_size, void* d_ws, size_t ws_size,
                              hipStream_t stream) {
    const float* x   = (const float*)d_in[0];
    const int*   ei  = (const int*)d_in[1];
    const int*   bat = (const int*)d_in[2];
    const float* W1  = (const float*)d_in[3];
    const float* b1  = (const float*)d_in[4];
    const float* W2  = (const float*)d_in[5];
    const float* b2  = (const float*)d_in[6];
    const float* W3  = (const float*)d_in[7];
    const float* b3  = (const float*)d_in[8];
    const float* Wc1 = (const float*)d_in[9];
    const float* bc1 = (const float*)d_in[10];
    const float* Wc2 = (const float*)d_in[11];
    const float* bc2 = (const float*)d_in[12];

    const int N  = in_sizes[0] / 128;
    const int E  = in_sizes[1] / 2;
    const int NG = out_size / 10;
    const int B  = (N + 63) >> 6;  // <= BMAX for N <= 131072
    const int* srcp = ei;
    const int* dstp = ei + E;

    char* ws = (char*)d_ws;
    size_t off = 0;
    auto alloc = [&](size_t bytes) -> void* {
        void* p = ws + off;
        off += (bytes + 255) / 256 * 256;
        return p;
    };
    unsigned int* G = (unsigned int*)alloc((size_t)N * 32 * 4);  // bf16x2 gather table
    float* H      = (float*)alloc((size_t)N * 64 * 4);
    int*   pairs  = (int*)H;  // alias: pairs (E ints) dead before first aggregate writes H
    int*   csr    = (int*)alloc((size_t)E * 4);
    int*   rp     = (int*)alloc((size_t)(N + 1) * 4);
    float* dinv   = (float*)alloc((size_t)N * 4);
    int*   bcnt   = (int*)alloc((size_t)BMAX * 4);
    int*   prp    = (int*)alloc((size_t)(BMAX + 1) * 4);
    int*   cntmat = (int*)alloc((size_t)BMAX * NBLK * 4);  // 2 MB
    (void)ws_size; (void)n_in;

    // --- CSR build (two-level multisplit) ---
    const int chunk = (E + NBLK - 1) / NBLK;
    part_hist<<<NBLK, 1024, 0, stream>>>(dstp, cntmat, E, B, chunk);
    part_scan<<<(B + 3) / 4, 256, 0, stream>>>(cntmat, bcnt, B);
    bucket_scan<<<1, 256, 0, stream>>>(bcnt, prp, B);
    part_scatter<<<NBLK, 1024, 0, stream>>>(srcp, dstp, cntmat, prp, pairs, E, B, chunk);
    csr_build<<<B, 256, 0, stream>>>(pairs, prp, rp, dinv, csr, N, B, E);

    // --- 3 GCN layers: GEMM (bf16x2-packed G out) + pull-aggregate ---
    gemm_dinv<128><<<(N + 63) / 64, 256, 0, stream>>>(x, W1, dinv, G, N);
    aggregate<<<(N + 3) / 4, 256, 0, stream>>>(G, rp, csr, dinv, b1, H, N);
    gemm_dinv<64><<<(N + 63) / 64, 256, 0, stream>>>(H, W2, dinv, G, N);
    aggregate<<<(N + 3) / 4, 256, 0, stream>>>(G, rp, csr, dinv, b2, H, N);
    gemm_dinv<64><<<(N + 63) / 64, 256, 0, stream>>>(H, W3, dinv, G, N);
    aggregate<<<(N + 3) / 4, 256, 0, stream>>>(G, rp, csr, dinv, b3, H, N);

    // --- fused mean-pool + classifier ---
    pool_classify<<<NG, 256, 0, stream>>>(H, bat, Wc1, bc1, Wc2, bc2, (float*)d_out, N);
}